// Round 5
// baseline (1492.012 us; speedup 1.0000x reference)
//
#include <hip/hip_runtime.h>
#include <math.h>

typedef __attribute__((ext_vector_type(8))) short short8;
typedef __attribute__((ext_vector_type(4))) short short4v;
typedef __attribute__((ext_vector_type(4))) float f32x4;

union U32S8 { unsigned u[4]; short8 s8; ushort e[8]; short4v h[2]; };

#define BATCH 128
#define NHIS  50
#define NCAND 5
#define KP    320   // padded K stride for transposed weights (elems)
#define XS    328   // LDS row stride (encode_user)
#define NQKV  912   // padded N for [Wq|Wk|Wv] weight buffer
#define NWP   208   // padded N for Wp
#define NQK   600   // Q|K row-major intermediate width
#define CTS   320   // ctx row stride (elems)
#define SCALE 0.22360679774997896f  // 1/sqrt(20)

__device__ __forceinline__ ushort f2bf(float f) {
    union { float f; unsigned u; } v; v.f = f;
    return (ushort)((v.u + 0x7fffu + ((v.u >> 16) & 1u)) >> 16);
}
__device__ __forceinline__ unsigned pack2bf(float lo, float hi) {
    return (unsigned)f2bf(lo) | ((unsigned)f2bf(hi) << 16);
}
__device__ __forceinline__ float bf2f(ushort u) {
    union { float f; unsigned u; } v; v.u = ((unsigned)u) << 16;
    return v.f;
}

// ---------- weight prep: W[k][n] fp32 -> WT[p][n][k] bf16, zero-padded ----------
__global__ void prep_qkv(const float* __restrict__ Wq, const float* __restrict__ Wk,
                         const float* __restrict__ Wv, ushort* __restrict__ dst, int P) {
    size_t i = (size_t)blockIdx.x * 256 + threadIdx.x;
    size_t total = (size_t)P * NQKV * KP;
    if (i >= total) return;
    int k = (int)(i % KP);
    int n = (int)((i / KP) % NQKV);
    int p = (int)(i / ((size_t)KP * NQKV));
    float v = 0.f;
    if (k < 300 && n < 900) {
        const float* W = (n < 300) ? Wq : (n < 600 ? Wk : Wv);
        int nn = n % 300;
        v = W[((size_t)p * 300 + k) * 300 + nn];
    }
    dst[i] = f2bf(v);
}

__global__ void prep_wp(const float* __restrict__ Wp, ushort* __restrict__ dst, int P) {
    size_t i = (size_t)blockIdx.x * 256 + threadIdx.x;
    size_t total = (size_t)P * NWP * KP;
    if (i >= total) return;
    int k = (int)(i % KP);
    int a = (int)((i / KP) % NWP);
    int p = (int)(i / ((size_t)KP * NWP));
    float v = 0.f;
    if (k < 300 && a < 200) v = Wp[((size_t)p * 300 + k) * 200 + a];
    dst[i] = f2bf(v);
}

// ---------- K2: batched QKV GEMM per p ----------
// qk:  [P_chunk][3840][600] bf16 (Q cols 0..299, K cols 300..599)
// vt:  [P_chunk][128][15][20][32] bf16  (V transposed: [h][vj][l], l-pad 30..31 untouched)
__global__ __launch_bounds__(256, 4)
void qkv_gemm(const float* __restrict__ emb, const int* __restrict__ tokens,
              const ushort* __restrict__ wt,   // [P_all][NQKV][KP]
              ushort* __restrict__ qk, ushort* __restrict__ vt,
              int p0, int P_all)
{
    __shared__ ushort At[2][128][40];
    __shared__ ushort Bt[2][128][40];
    __shared__ int TOK[128];

    const int bid   = blockIdx.x;
    const int ntile = bid & 7;
    const int mtile = (bid >> 3) % 30;
    const int p_l   = bid / 240;
    const int p_g   = p0 + p_l;
    const int t     = threadIdx.x;
    const int wave  = t >> 6, lane = t & 63;
    const int r = lane & 15, g = lane >> 4;
    const int qm = wave >> 1, qn = wave & 1;

    if (t < 128) {
        int row = mtile * 128 + t;
        int b = row / 30, l = row - b * 30;
        TOK[t] = tokens[((size_t)b * P_all + p_g) * 30 + l];
    }
    __syncthreads();

    const ushort* wtp = wt + (size_t)p_g * NQKV * KP;
    const int rr = t >> 1, half = t & 1;

    auto stage = [&](int ks, int buf) {
        {
            int base = ks * 32 + half * 16;
            ushort* dst = &At[buf][rr][half * 16];
            const float* src = emb + (size_t)TOK[rr] * 300 + base;
            if (base + 16 <= 300) {
                float4 v0 = *(const float4*)(src);
                float4 v1 = *(const float4*)(src + 4);
                float4 v2 = *(const float4*)(src + 8);
                float4 v3 = *(const float4*)(src + 12);
                unsigned* d = (unsigned*)dst;
                d[0] = pack2bf(v0.x, v0.y); d[1] = pack2bf(v0.z, v0.w);
                d[2] = pack2bf(v1.x, v1.y); d[3] = pack2bf(v1.z, v1.w);
                d[4] = pack2bf(v2.x, v2.y); d[5] = pack2bf(v2.z, v2.w);
                d[6] = pack2bf(v3.x, v3.y); d[7] = pack2bf(v3.z, v3.w);
            } else {
                #pragma unroll
                for (int c = 0; c < 16; ++c)
                    dst[c] = (base + c < 300) ? f2bf(src[c]) : (ushort)0;
            }
        }
        {
            int n = ntile * 128 + rr;
            ushort* dst = &Bt[buf][rr][half * 16];
            if (n < NQKV) {
                const ushort* srcb = wtp + (size_t)n * KP + ks * 32 + half * 16;
                ((short8*)dst)[0] = ((const short8*)srcb)[0];
                ((short8*)dst)[1] = ((const short8*)srcb)[1];
            } else {
                short8 z = {0,0,0,0,0,0,0,0};
                ((short8*)dst)[0] = z;
                ((short8*)dst)[1] = z;
            }
        }
    };

    f32x4 acc[4][4];
    #pragma unroll
    for (int i = 0; i < 4; ++i)
        #pragma unroll
        for (int j = 0; j < 4; ++j)
            acc[i][j] = (f32x4){0.f, 0.f, 0.f, 0.f};

    stage(0, 0);
    __syncthreads();
    int buf = 0;
    for (int ks = 0; ks < 10; ++ks) {
        if (ks < 9) stage(ks + 1, buf ^ 1);
        short8 af[4], bfr[4];
        #pragma unroll
        for (int fi = 0; fi < 4; ++fi)
            af[fi] = *(const short8*)&At[buf][qm * 64 + fi * 16 + r][8 * g];
        #pragma unroll
        for (int fj = 0; fj < 4; ++fj)
            bfr[fj] = *(const short8*)&Bt[buf][qn * 64 + fj * 16 + r][8 * g];
        #pragma unroll
        for (int fi = 0; fi < 4; ++fi)
            #pragma unroll
            for (int fj = 0; fj < 4; ++fj)
                acc[fi][fj] = __builtin_amdgcn_mfma_f32_16x16x32_bf16(af[fi], bfr[fj], acc[fi][fj], 0, 0, 0);
        __syncthreads();
        buf ^= 1;
    }

    ushort* qkp = qk + (size_t)p_l * 3840 * NQK;
    ushort* vtp = vt + (size_t)p_l * BATCH * 15 * 640;
    #pragma unroll
    for (int fi = 0; fi < 4; ++fi) {
        #pragma unroll
        for (int fj = 0; fj < 4; ++fj) {
            int n = ntile * 128 + qn * 64 + fj * 16 + r;
            if (n < NQK) {
                #pragma unroll
                for (int j = 0; j < 4; ++j) {
                    int row = mtile * 128 + qm * 64 + fi * 16 + 4 * g + j;
                    qkp[(size_t)row * NQK + n] = f2bf(acc[fi][fj][j]);
                }
            } else if (n < 900) {
                int vj = n - 600;
                int h = vj / 20, jj = vj - h * 20;
                #pragma unroll
                for (int j = 0; j < 4; ++j) {
                    int row = mtile * 128 + qm * 64 + fi * 16 + 4 * g + j;
                    int b = row / 30, l = row - b * 30;
                    vtp[((size_t)b * 15 + h) * 640 + jj * 32 + l] = f2bf(acc[fi][fj][j]);
                }
            }
        }
    }
}

// ---------- K3: attention -> ctx (pure register, no LDS) ----------
__device__ __forceinline__ short8 load_qk_frag(const ushort* rowptr, int colbase, int g, bool rowvalid) {
    U32S8 v;
    v.s8 = (short8){0,0,0,0,0,0,0,0};
    if (rowvalid && g < 3) {
        const ushort* src = rowptr + colbase;
        if (g < 2) {
            v.h[0] = *(const short4v*)src;
            v.h[1] = *(const short4v*)(src + 4);
        } else {
            v.h[0] = *(const short4v*)src;
        }
    }
    return v.s8;
}

__global__ __launch_bounds__(256)
void attn_ctx(const ushort* __restrict__ qk,   // [P_chunk][3840][600]
              const ushort* __restrict__ vt,   // [P_chunk][128][15][640]
              ushort* __restrict__ ctx,        // [P_chunk][128][32][320]
              int)
{
    const int tid  = threadIdx.x;
    const int wave = tid >> 6;
    const int lane = tid & 63;
    const int r = lane & 15, g = lane >> 4;
    const int p_l = blockIdx.x / BATCH;
    const int b   = blockIdx.x % BATCH;

    const ushort* qb  = qk + ((size_t)p_l * BATCH + b) * 30 * NQK;
    const ushort* vb  = vt + ((size_t)p_l * BATCH + b) * 15 * 640;
    ushort* cb = ctx + ((size_t)p_l * BATCH + b) * 32 * CTS;

    // zero pad rows 30,31 and col pads (once per block)
    for (int i = tid; i < 2 * CTS; i += 256) cb[30 * CTS + i] = 0;
    for (int i = tid; i < 32 * 20; i += 256) {
        int row = i / 20, c = 300 + i % 20;
        cb[row * CTS + c] = 0;
    }

    for (int hp = 0; hp < 4; ++hp) {
        int head = wave + 4 * hp;
        if (head < 15) {
            short8 q0 = load_qk_frag(qb + (size_t)(r) * NQK,      head * 20 + 8 * g, g, r < 30);
            short8 q1 = load_qk_frag(qb + (size_t)(16 + r) * NQK, head * 20 + 8 * g, g, 16 + r < 30);
            short8 k0 = load_qk_frag(qb + (size_t)(r) * NQK,      300 + head * 20 + 8 * g, g, r < 30);
            short8 k1 = load_qk_frag(qb + (size_t)(16 + r) * NQK, 300 + head * 20 + 8 * g, g, 16 + r < 30);
            short8 vf0 = *(const short8*)&vb[head * 640 + r * 32 + 8 * g];
            short8 vf1 = (16 + r < 20) ? *(const short8*)&vb[head * 640 + (16 + r) * 32 + 8 * g]
                                       : (short8){0,0,0,0,0,0,0,0};

            f32x4 s0m0 = {0,0,0,0}, s0m1 = {0,0,0,0}, s1m0 = {0,0,0,0}, s1m1 = {0,0,0,0};
            s0m0 = __builtin_amdgcn_mfma_f32_16x16x32_bf16(k0, q0, s0m0, 0, 0, 0);
            s0m1 = __builtin_amdgcn_mfma_f32_16x16x32_bf16(k1, q0, s0m1, 0, 0, 0);
            s1m0 = __builtin_amdgcn_mfma_f32_16x16x32_bf16(k0, q1, s1m0, 0, 0, 0);
            s1m1 = __builtin_amdgcn_mfma_f32_16x16x32_bf16(k1, q1, s1m1, 0, 0, 0);

            float mx0 = -1e30f, mx1 = -1e30f;
            #pragma unroll
            for (int j = 0; j < 4; ++j) {
                s0m0[j] *= SCALE; s1m0[j] *= SCALE;
                float v01 = (16 + 4 * g + j < 30) ? s0m1[j] * SCALE : -1e30f;
                float v11 = (16 + 4 * g + j < 30) ? s1m1[j] * SCALE : -1e30f;
                s0m1[j] = v01; s1m1[j] = v11;
                mx0 = fmaxf(mx0, fmaxf(s0m0[j], v01));
                mx1 = fmaxf(mx1, fmaxf(s1m0[j], v11));
            }
            mx0 = fmaxf(mx0, __shfl_xor(mx0, 16, 64));
            mx0 = fmaxf(mx0, __shfl_xor(mx0, 32, 64));
            mx1 = fmaxf(mx1, __shfl_xor(mx1, 16, 64));
            mx1 = fmaxf(mx1, __shfl_xor(mx1, 32, 64));
            float sm0 = 0.f, sm1 = 0.f;
            #pragma unroll
            for (int j = 0; j < 4; ++j) {
                s0m0[j] = __expf(s0m0[j] - mx0); s0m1[j] = __expf(s0m1[j] - mx0);
                s1m0[j] = __expf(s1m0[j] - mx1); s1m1[j] = __expf(s1m1[j] - mx1);
                sm0 += s0m0[j] + s0m1[j];
                sm1 += s1m0[j] + s1m1[j];
            }
            sm0 += __shfl_xor(sm0, 16, 64); sm0 += __shfl_xor(sm0, 32, 64);
            sm1 += __shfl_xor(sm1, 16, 64); sm1 += __shfl_xor(sm1, 32, 64);
            float inv0 = 1.0f / sm0, inv1 = 1.0f / sm1;

            unsigned pk000 = pack2bf(s0m0[0] * inv0, s0m0[1] * inv0);
            unsigned pk001 = pack2bf(s0m0[2] * inv0, s0m0[3] * inv0);
            unsigned pk010 = pack2bf(s0m1[0] * inv0, s0m1[1] * inv0);
            unsigned pk011 = pack2bf(s0m1[2] * inv0, s0m1[3] * inv0);
            unsigned pk100 = pack2bf(s1m0[0] * inv1, s1m0[1] * inv1);
            unsigned pk101 = pack2bf(s1m0[2] * inv1, s1m0[3] * inv1);
            unsigned pk110 = pack2bf(s1m1[0] * inv1, s1m1[1] * inv1);
            unsigned pk111 = pack2bf(s1m1[2] * inv1, s1m1[3] * inv1);

            const int sA = r + 16 * (2 * (g & 1));
            const int sB = sA + 16;
            const bool hi = (g >> 1) != 0;
            #pragma unroll
            for (int lt = 0; lt < 2; ++lt) {
                unsigned q00 = lt ? pk100 : pk000, q01 = lt ? pk101 : pk001;
                unsigned q10 = lt ? pk110 : pk010, q11 = lt ? pk111 : pk011;
                unsigned a0 = __shfl((int)q00, sA, 64), a1 = __shfl((int)q01, sA, 64);
                unsigned a2 = __shfl((int)q10, sA, 64), a3 = __shfl((int)q11, sA, 64);
                unsigned b0 = __shfl((int)q00, sB, 64), b1 = __shfl((int)q01, sB, 64);
                unsigned b2 = __shfl((int)q10, sB, 64), b3 = __shfl((int)q11, sB, 64);
                U32S8 pf;
                pf.u[0] = hi ? a2 : a0;
                pf.u[1] = hi ? a3 : a1;
                pf.u[2] = hi ? b2 : b0;
                pf.u[3] = hi ? b3 : b1;
                int lrow = lt * 16 + r;
                #pragma unroll
                for (int nt = 0; nt < 2; ++nt) {
                    short8 vf = nt ? vf1 : vf0;
                    f32x4 c = {0.f, 0.f, 0.f, 0.f};
                    c = __builtin_amdgcn_mfma_f32_16x16x32_bf16(vf, pf.s8, c, 0, 0, 0);
                    if (lrow < 30) {
                        #pragma unroll
                        for (int j = 0; j < 4; ++j) {
                            int vj = nt * 16 + 4 * g + j;
                            if (vj < 20)
                                cb[lrow * CTS + head * 20 + vj] = f2bf(c[j]);
                        }
                    }
                }
            }
        }
    }
}

// ---------- K4: pooling GEMM per p ----------
// block: 128 rows (4 instances) x 208 cols, K=320. Wp staged in LDS once per block.
__global__ __launch_bounds__(256, 2)
void pool_gemm(const ushort* __restrict__ ctx,   // [P_chunk][128][32][320]
               const ushort* __restrict__ wt_wp, // [P_all][208][320]
               const float* __restrict__ bp, const float* __restrict__ qv,
               float* __restrict__ out,          // [B][P_all][300]
               int p0, int P_all)
{
    __shared__ ushort Bt[2][208 * 40];
    __shared__ float  logit[128];
    __shared__ float  aw[128];

    const int tid  = threadIdx.x;
    const int wave = tid >> 6;
    const int lane = tid & 63;
    const int r = lane & 15, g = lane >> 4;
    const int p_l   = blockIdx.x >> 5;
    const int mtile = blockIdx.x & 31;
    const int p_g   = p0 + p_l;

    const ushort* cbase = ctx + (size_t)p_l * BATCH * 32 * CTS + (size_t)mtile * 128 * CTS;
    const ushort* wpp = wt_wp + (size_t)p_g * NWP * KP;

    auto stageB = [&](int ks, int buf) {
        for (int i = tid; i < 832; i += 256) {
            int n = i >> 2, kk = (i & 3) * 8;
            *(short8*)&Bt[buf][n * 40 + kk] = *(const short8*)&wpp[(size_t)n * KP + ks * 32 + kk];
        }
    };

    // per-lane col constants
    float bpr[13], qvr[13];
    #pragma unroll
    for (int nf = 0; nf < 13; ++nf) {
        int col = nf * 16 + r;
        bpr[nf] = (col < 200) ? bp[p_g * 200 + col] : 0.f;
        qvr[nf] = (col < 200) ? qv[p_g * 200 + col] : 0.f;
    }

    f32x4 acc[2][13];
    #pragma unroll
    for (int mf = 0; mf < 2; ++mf)
        #pragma unroll
        for (int nf = 0; nf < 13; ++nf)
            acc[mf][nf] = (f32x4){0.f, 0.f, 0.f, 0.f};

    stageB(0, 0);
    __syncthreads();
    int buf = 0;
    for (int ks = 0; ks < 10; ++ks) {
        if (ks < 9) stageB(ks + 1, buf ^ 1);
        short8 af[2];
        #pragma unroll
        for (int mf = 0; mf < 2; ++mf)
            af[mf] = *(const short8*)&cbase[(size_t)(wave * 32 + mf * 16 + r) * CTS + ks * 32 + 8 * g];
        #pragma unroll
        for (int mf = 0; mf < 2; ++mf)
            #pragma unroll
            for (int nf = 0; nf < 13; ++nf) {
                short8 bf = *(const short8*)&Bt[buf][(nf * 16 + r) * 40 + 8 * g];
                acc[mf][nf] = __builtin_amdgcn_mfma_f32_16x16x32_bf16(af[mf], bf, acc[mf][nf], 0, 0, 0);
            }
        __syncthreads();
        buf ^= 1;
    }

    // logits: tanh(acc + bp) . qv, reduce over cols
    #pragma unroll
    for (int mf = 0; mf < 2; ++mf) {
        #pragma unroll
        for (int j = 0; j < 4; ++j) {
            float s = 0.f;
            #pragma unroll
            for (int nf = 0; nf < 13; ++nf)
                s += tanhf(acc[mf][nf][j] + bpr[nf]) * qvr[nf];
            s += __shfl_xor(s, 1, 64);
            s += __shfl_xor(s, 2, 64);
            s += __shfl_xor(s, 4, 64);
            s += __shfl_xor(s, 8, 64);
            if (r == 0) logit[wave * 32 + mf * 16 + 4 * g + j] = s;
        }
    }
    __syncthreads();

    // per-instance softmax: wave w -> instance w (32 rows, 30 valid)
    {
        float x = (lane < 30) ? logit[wave * 32 + lane] : -1e30f;
        float mx = x;
        #pragma unroll
        for (int off = 1; off < 64; off <<= 1) mx = fmaxf(mx, __shfl_xor(mx, off, 64));
        float e = (lane < 30) ? __expf(x - mx) : 0.f;
        float sm = e;
        #pragma unroll
        for (int off = 1; off < 64; off <<= 1) sm += __shfl_xor(sm, off, 64);
        if (lane < 32) aw[wave * 32 + lane] = e / sm;
    }
    __syncthreads();

    // out[b][p][c] = sum_l a[l] * ctx[l][c]
    for (int idx = tid; idx < 4 * 300; idx += 256) {
        int inst = idx / 300, c = idx - inst * 300;
        const ushort* crow = cbase + (size_t)inst * 32 * CTS + c;
        float o = 0.f;
        #pragma unroll
        for (int l = 0; l < 30; ++l)
            o = fmaf(aw[inst * 32 + l], bf2f(crow[(size_t)l * CTS]), o);
        int b = mtile * 4 + inst;
        out[((size_t)b * P_all + p_g) * 300 + c] = o;
    }
}

// ---------- user encoder, L=50 (unchanged) ----------
#define QS 488
__global__ __launch_bounds__(512, 1)
void encode_user(const float* __restrict__ news_enc, const ushort* __restrict__ wt_qkv,
                 const ushort* __restrict__ wt_wp, const float* __restrict__ bp,
                 const float* __restrict__ qv, float* __restrict__ user_rep)
{
    __shared__ ushort Xb[64 * XS];
    __shared__ ushort Cb[64 * XS];
    __shared__ ushort Qh[64 * 32];
    __shared__ ushort Kh[64 * 32];
    __shared__ ushort VTh[32 * 64];
    __shared__ float  SC[64 * 64];
    __shared__ ushort Pb[64 * 64];
    __shared__ float  SL[64];

    const int tid  = threadIdx.x;
    const int wave = tid >> 6;
    const int lane = tid & 63;
    const int r = lane & 15, g = lane >> 4;
    const int b = blockIdx.x;

    for (int i = tid; i < 64 * XS; i += 512) { Xb[i] = 0; Cb[i] = 0; }
    for (int i = tid; i < 64 * 32; i += 512) { Qh[i] = 0; Kh[i] = 0; }
    for (int i = tid; i < 32 * 64; i += 512) VTh[i] = 0;
    for (int i = tid; i < 64 * 64; i += 512) Pb[i] = 0;
    if (tid < 64) SL[tid] = 0.f;
    __syncthreads();

    for (int i = tid; i < 50 * 300; i += 512) {
        int l = i / 300, d = i - l * 300;
        Xb[l * XS + d] = f2bf(news_enc[((size_t)b * 50 + l) * 300 + d]);
    }
    __syncthreads();

    for (int h = 0; h < 15; ++h) {
        const int nt = wave >> 2, mt = wave & 3;
        for (int seg = 0; seg < 3; ++seg) {
            f32x4 acc = {0.f, 0.f, 0.f, 0.f};
            int n = seg * 300 + h * 20 + nt * 16 + r;
            const ushort* wrow = wt_qkv + (size_t)n * KP + 8 * g;
            short8 breg[10];
            #pragma unroll
            for (int ks = 0; ks < 10; ++ks) breg[ks] = *(const short8*)(wrow + 32 * ks);
            const ushort* xrow = &Xb[(mt * 16 + r) * XS + 8 * g];
            #pragma unroll
            for (int ks = 0; ks < 10; ++ks) {
                short8 a = *(const short8*)(xrow + 32 * ks);
                acc = __builtin_amdgcn_mfma_f32_16x16x32_bf16(a, breg[ks], acc, 0, 0, 0);
            }
            int c = nt * 16 + r;
            if (c < 20) {
                #pragma unroll
                for (int j = 0; j < 4; ++j) {
                    int row = mt * 16 + 4 * g + j;
                    ushort v = f2bf(acc[j]);
                    if (seg == 0)      Qh[row * 32 + c] = v;
                    else if (seg == 1) Kh[row * 32 + c] = v;
                    else               VTh[c * 64 + row] = v;
                }
            }
        }
        __syncthreads();
        for (int it = 0; it < 2; ++it) {
            int tile = wave + 8 * it;
            int smt = tile & 3, snt = tile >> 2;
            short8 a  = *(const short8*)&Qh[(smt * 16 + r) * 32 + 8 * g];
            short8 bb = *(const short8*)&Kh[(snt * 16 + r) * 32 + 8 * g];
            f32x4 acc = {0.f, 0.f, 0.f, 0.f};
            acc = __builtin_amdgcn_mfma_f32_16x16x32_bf16(a, bb, acc, 0, 0, 0);
            #pragma unroll
            for (int j = 0; j < 4; ++j)
                SC[(smt * 16 + 4 * g + j) * 64 + snt * 16 + r] = acc[j] * SCALE;
        }
        __syncthreads();
        if (tid < 50) {
            float* row = &SC[tid * 64];
            float mx = -1e30f;
            for (int m = 0; m < 50; ++m) mx = fmaxf(mx, row[m]);
            float sum = 0.f;
            for (int m = 0; m < 50; ++m) { float e = __expf(row[m] - mx); row[m] = e; sum += e; }
            float inv = 1.0f / sum;
            ushort* prow = &Pb[tid * 64];
            for (int m = 0; m < 64; ++m) prow[m] = (m < 50) ? f2bf(row[m] * inv) : (ushort)0;
        }
        __syncthreads();
        {
            int cmt = wave & 3, cnt = wave >> 2;
            f32x4 acc = {0.f, 0.f, 0.f, 0.f};
            #pragma unroll
            for (int ks = 0; ks < 2; ++ks) {
                short8 a  = *(const short8*)&Pb[(cmt * 16 + r) * 64 + 32 * ks + 8 * g];
                short8 bb = *(const short8*)&VTh[(cnt * 16 + r) * 64 + 32 * ks + 8 * g];
                acc = __builtin_amdgcn_mfma_f32_16x16x32_bf16(a, bb, acc, 0, 0, 0);
            }
            int vj = cnt * 16 + r;
            if (vj < 20) {
                #pragma unroll
                for (int j = 0; j < 4; ++j)
                    Cb[(cmt * 16 + 4 * g + j) * XS + h * 20 + vj] = f2bf(acc[j]);
            }
        }
        __syncthreads();
    }

    for (int tile = wave; tile < 52; tile += 8) {
        int nt = tile >> 2, mt = tile & 3;
        f32x4 acc = {0.f, 0.f, 0.f, 0.f};
        const ushort* wrow = wt_wp + (size_t)(nt * 16 + r) * KP + 8 * g;
        short8 breg[10];
        #pragma unroll
        for (int ks = 0; ks < 10; ++ks) breg[ks] = *(const short8*)(wrow + 32 * ks);
        const ushort* crow = &Cb[(mt * 16 + r) * XS + 8 * g];
        #pragma unroll
        for (int ks = 0; ks < 10; ++ks) {
            short8 a = *(const short8*)(crow + 32 * ks);
            acc = __builtin_amdgcn_mfma_f32_16x16x32_bf16(a, breg[ks], acc, 0, 0, 0);
        }
        int ai = nt * 16 + r;
        if (ai < 200) {
            float bpv = bp[ai], qvv = qv[ai];
            #pragma unroll
            for (int j = 0; j < 4; ++j)
                atomicAdd(&SL[mt * 16 + 4 * g + j], tanhf(acc[j] + bpv) * qvv);
        }
    }
    __syncthreads();
    if (tid == 0) {
        float mx = -1e30f;
        for (int l = 0; l < 50; ++l) mx = fmaxf(mx, SL[l]);
        float s = 0.f;
        for (int l = 0; l < 50; ++l) { float e = __expf(SL[l] - mx); SL[l] = e; s += e; }
        float inv = 1.0f / s;
        for (int l = 0; l < 50; ++l) SL[l] *= inv;
    }
    __syncthreads();
    for (int c = tid; c < 300; c += 512) {
        float o = 0.f;
        for (int l = 0; l < 50; ++l) o = fmaf(SL[l], bf2f(Cb[l * XS + c]), o);
        user_rep[(size_t)b * 300 + c] = o;
    }
}

// ---------- final scoring ----------
__global__ __launch_bounds__(320)
void score_kernel(const float* __restrict__ user_rep, const float* __restrict__ cand_enc,
                  float* __restrict__ out)
{
    __shared__ float sc[NCAND];
    int b = blockIdx.x;
    int w = threadIdx.x >> 6;
    int lane = threadIdx.x & 63;
    float partial = 0.f;
    for (int d = lane; d < 300; d += 64)
        partial = fmaf(user_rep[b * 300 + d], cand_enc[((size_t)b * NCAND + w) * 300 + d], partial);
    for (int off = 32; off > 0; off >>= 1)
        partial += __shfl_down(partial, off, 64);
    if (lane == 0) sc[w] = partial;
    __syncthreads();
    if (threadIdx.x == 0) {
        float mx = -1e30f;
        for (int c = 0; c < NCAND; ++c) mx = fmaxf(mx, sc[c]);
        float s = 0.f; float e[NCAND];
        for (int c = 0; c < NCAND; ++c) { e[c] = __expf(sc[c] - mx); s += e[c]; }
        float inv = 1.0f / s;
        for (int c = 0; c < NCAND; ++c) out[b * NCAND + c] = e[c] * inv;
    }
}

extern "C" void kernel_launch(void* const* d_in, const int* in_sizes, int n_in,
                              void* d_out, int out_size, void* d_ws, size_t ws_size,
                              hipStream_t stream) {
    const int*   news_input = (const int*)d_in[0];
    const int*   candidates = (const int*)d_in[1];
    const float* emb        = (const float*)d_in[2];
    const float* his_Wq  = (const float*)d_in[3];
    const float* his_Wk  = (const float*)d_in[4];
    const float* his_Wv  = (const float*)d_in[5];
    const float* his_Wp  = (const float*)d_in[6];
    const float* his_bp  = (const float*)d_in[7];
    const float* his_qv  = (const float*)d_in[8];
    const float* cand_Wq = (const float*)d_in[9];
    const float* cand_Wk = (const float*)d_in[10];
    const float* cand_Wv = (const float*)d_in[11];
    const float* cand_Wp = (const float*)d_in[12];
    const float* cand_bp = (const float*)d_in[13];
    const float* cand_qv = (const float*)d_in[14];
    const float* usr_Wq  = (const float*)d_in[15];
    const float* usr_Wk  = (const float*)d_in[16];
    const float* usr_Wv  = (const float*)d_in[17];
    const float* usr_Wp  = (const float*)d_in[18];
    const float* usr_bp  = (const float*)d_in[19];
    const float* usr_qv  = (const float*)d_in[20];
    float* out = (float*)d_out;

    char* ws = (char*)d_ws;
    float* news_enc = (float*)ws;                 ws += (size_t)BATCH * NHIS * 300 * 4;
    float* cand_enc = (float*)ws;                 ws += (size_t)BATCH * NCAND * 300 * 4;
    float* user_rep = (float*)ws;                 ws += (size_t)BATCH * 300 * 4;
    ushort* his_qkvT  = (ushort*)ws;              ws += (size_t)NHIS * NQKV * KP * 2;
    ushort* his_wpT   = (ushort*)ws;              ws += (size_t)NHIS * NWP  * KP * 2;
    ushort* cand_qkvT = (ushort*)ws;              ws += (size_t)NCAND * NQKV * KP * 2;
    ushort* cand_wpT  = (ushort*)ws;              ws += (size_t)NCAND * NWP  * KP * 2;
    ushort* usr_qkvT  = (ushort*)ws;              ws += (size_t)NQKV * KP * 2;
    ushort* usr_wpT   = (ushort*)ws;              ws += (size_t)NWP  * KP * 2;

    size_t used = (size_t)(ws - (char*)d_ws);
    size_t avail = (ws_size > used) ? (ws_size - used) : 0;
    // per-p: qk [3840][600] + vt [128][15][640] + ctx [128][32][320], all bf16
    size_t qk_pp  = (size_t)3840 * NQK * 2;
    size_t vt_pp  = (size_t)BATCH * 15 * 640 * 2;
    size_t ctx_pp = (size_t)BATCH * 32 * CTS * 2;
    size_t per_p  = qk_pp + vt_pp + ctx_pp;
    int CP = 10;
    if (avail >= 50 * per_p) CP = 50;
    else if (avail >= 25 * per_p) CP = 25;

    ushort* qk_ws  = (ushort*)ws;
    ushort* vt_ws  = qk_ws + (size_t)CP * 3840 * NQK;
    ushort* ctx_ws = vt_ws + (size_t)CP * BATCH * 15 * 640;

    auto blocks = [](size_t total) { return (int)((total + 255) / 256); };

    prep_qkv<<<blocks((size_t)NHIS  * NQKV * KP), 256, 0, stream>>>(his_Wq,  his_Wk,  his_Wv,  his_qkvT,  NHIS);
    prep_qkv<<<blocks((size_t)NCAND * NQKV * KP), 256, 0, stream>>>(cand_Wq, cand_Wk, cand_Wv, cand_qkvT, NCAND);
    prep_qkv<<<blocks((size_t)1     * NQKV * KP), 256, 0, stream>>>(usr_Wq,  usr_Wk,  usr_Wv,  usr_qkvT,  1);
    prep_wp <<<blocks((size_t)NHIS  * NWP  * KP), 256, 0, stream>>>(his_Wp,  his_wpT,  NHIS);
    prep_wp <<<blocks((size_t)NCAND * NWP  * KP), 256, 0, stream>>>(cand_Wp, cand_wpT, NCAND);
    prep_wp <<<blocks((size_t)1     * NWP  * KP), 256, 0, stream>>>(usr_Wp,  usr_wpT,  1);

    for (int p0 = 0; p0 < NHIS; p0 += CP) {
        int cp = (NHIS - p0 < CP) ? (NHIS - p0) : CP;
        qkv_gemm<<<cp * 240, 256, 0, stream>>>(emb, news_input, his_qkvT, qk_ws, vt_ws, p0, NHIS);
        attn_ctx<<<cp * BATCH, 256, 0, stream>>>(qk_ws, vt_ws, ctx_ws, 0);
        pool_gemm<<<cp * 32, 256, 0, stream>>>(ctx_ws, his_wpT, his_bp, his_qv, news_enc, p0, NHIS);
    }
    qkv_gemm<<<NCAND * 240, 256, 0, stream>>>(emb, candidates, cand_qkvT, qk_ws, vt_ws, 0, NCAND);
    attn_ctx<<<NCAND * BATCH, 256, 0, stream>>>(qk_ws, vt_ws, ctx_ws, 0);
    pool_gemm<<<NCAND * 32, 256, 0, stream>>>(ctx_ws, cand_wpT, cand_bp, cand_qv, cand_enc, 0, NCAND);

    encode_user<<<BATCH, 512, 0, stream>>>(news_enc, usr_qkvT, usr_wpT, usr_bp, usr_qv, user_rep);
    score_kernel<<<BATCH, 320, 0, stream>>>(user_rep, cand_enc, out);
}

// Round 6
// 1407.732 us; speedup vs baseline: 1.0599x; 1.0599x over previous
//
#include <hip/hip_runtime.h>
#include <math.h>

typedef __attribute__((ext_vector_type(8))) short short8;
typedef __attribute__((ext_vector_type(4))) short short4v;
typedef __attribute__((ext_vector_type(4))) float f32x4;

union U32S8 { unsigned u[4]; short8 s8; ushort e[8]; short4v h[2]; };

#define BATCH 128
#define NHIS  50
#define NCAND 5
#define KP    320   // padded K stride for transposed weights (elems)
#define NQKV  912   // padded N for [Wq|Wk|Wv] weight buffer
#define NWP   208   // padded N for Wp
#define NQK   600   // Q|K row-major intermediate width
#define CTS   320   // ctx row stride (elems)
#define SCALE 0.22360679774997896f  // 1/sqrt(20)

__device__ __forceinline__ ushort f2bf(float f) {
    union { float f; unsigned u; } v; v.f = f;
    return (ushort)((v.u + 0x7fffu + ((v.u >> 16) & 1u)) >> 16);
}
__device__ __forceinline__ unsigned pack2bf(float lo, float hi) {
    return (unsigned)f2bf(lo) | ((unsigned)f2bf(hi) << 16);
}
__device__ __forceinline__ float bf2f(ushort u) {
    union { float f; unsigned u; } v; v.u = ((unsigned)u) << 16;
    return v.f;
}

// ---------- weight prep: W[k][n] fp32 -> WT[p][n][k] bf16, zero-padded ----------
__global__ void prep_qkv(const float* __restrict__ Wq, const float* __restrict__ Wk,
                         const float* __restrict__ Wv, ushort* __restrict__ dst, int P) {
    size_t i = (size_t)blockIdx.x * 256 + threadIdx.x;
    size_t total = (size_t)P * NQKV * KP;
    if (i >= total) return;
    int k = (int)(i % KP);
    int n = (int)((i / KP) % NQKV);
    int p = (int)(i / ((size_t)KP * NQKV));
    float v = 0.f;
    if (k < 300 && n < 900) {
        const float* W = (n < 300) ? Wq : (n < 600 ? Wk : Wv);
        int nn = n % 300;
        v = W[((size_t)p * 300 + k) * 300 + nn];
    }
    dst[i] = f2bf(v);
}

__global__ void prep_wp(const float* __restrict__ Wp, ushort* __restrict__ dst, int P) {
    size_t i = (size_t)blockIdx.x * 256 + threadIdx.x;
    size_t total = (size_t)P * NWP * KP;
    if (i >= total) return;
    int k = (int)(i % KP);
    int a = (int)((i / KP) % NWP);
    int p = (int)(i / ((size_t)KP * NWP));
    float v = 0.f;
    if (k < 300 && a < 200) v = Wp[((size_t)p * 300 + k) * 200 + a];
    dst[i] = f2bf(v);
}

// ---------- K2: batched QKV GEMM ----------
// LQ=30 (news/cand, GATHER via tokens): M = 3840 rows/p, V^T m-stride 32.
// LQ=50 (user, direct rows from news_enc): M = 6400 rows, V^T m-stride 64.
template<int LQ, bool GATHER>
__global__ __launch_bounds__(256, 4)
void qkv_gemm(const float* __restrict__ srcf, const int* __restrict__ tokens,
              const ushort* __restrict__ wt,   // [P_all][NQKV][KP]
              ushort* __restrict__ qk, ushort* __restrict__ vt,
              int p0, int P_all)
{
    constexpr int MT = (LQ == 30) ? 30 : 50;   // m-tiles per p
    constexpr int VS = (LQ == 30) ? 32 : 64;   // V^T m-stride

    __shared__ ushort At[2][128][40];
    __shared__ ushort Bt[2][128][40];
    __shared__ int TOK[128];

    const int bid   = blockIdx.x;
    const int ntile = bid & 7;
    const int mtile = (bid >> 3) % MT;
    const int p_l   = bid / (8 * MT);
    const int p_g   = p0 + p_l;
    const int t     = threadIdx.x;
    const int wave  = t >> 6, lane = t & 63;
    const int r = lane & 15, g = lane >> 4;
    const int qm = wave >> 1, qn = wave & 1;

    if (GATHER && t < 128) {
        int row = mtile * 128 + t;
        int b = row / LQ, l = row - b * LQ;
        TOK[t] = tokens[((size_t)b * P_all + p_g) * LQ + l];
    }
    __syncthreads();

    const ushort* wtp = wt + (size_t)p_g * NQKV * KP;
    const int rr = t >> 1, half = t & 1;

    auto stage = [&](int ks, int buf) {
        {
            int base = ks * 32 + half * 16;
            ushort* dst = &At[buf][rr][half * 16];
            const float* src;
            if (GATHER) src = srcf + (size_t)TOK[rr] * 300 + base;
            else        src = srcf + (size_t)(mtile * 128 + rr) * 300 + base;
            if (base + 16 <= 300) {
                float4 v0 = *(const float4*)(src);
                float4 v1 = *(const float4*)(src + 4);
                float4 v2 = *(const float4*)(src + 8);
                float4 v3 = *(const float4*)(src + 12);
                unsigned* d = (unsigned*)dst;
                d[0] = pack2bf(v0.x, v0.y); d[1] = pack2bf(v0.z, v0.w);
                d[2] = pack2bf(v1.x, v1.y); d[3] = pack2bf(v1.z, v1.w);
                d[4] = pack2bf(v2.x, v2.y); d[5] = pack2bf(v2.z, v2.w);
                d[6] = pack2bf(v3.x, v3.y); d[7] = pack2bf(v3.z, v3.w);
            } else {
                #pragma unroll
                for (int c = 0; c < 16; ++c)
                    dst[c] = (base + c < 300) ? f2bf(src[c]) : (ushort)0;
            }
        }
        {
            int n = ntile * 128 + rr;
            ushort* dst = &Bt[buf][rr][half * 16];
            if (n < NQKV) {
                const ushort* srcb = wtp + (size_t)n * KP + ks * 32 + half * 16;
                ((short8*)dst)[0] = ((const short8*)srcb)[0];
                ((short8*)dst)[1] = ((const short8*)srcb)[1];
            } else {
                short8 z = {0,0,0,0,0,0,0,0};
                ((short8*)dst)[0] = z;
                ((short8*)dst)[1] = z;
            }
        }
    };

    f32x4 acc[4][4];
    #pragma unroll
    for (int i = 0; i < 4; ++i)
        #pragma unroll
        for (int j = 0; j < 4; ++j)
            acc[i][j] = (f32x4){0.f, 0.f, 0.f, 0.f};

    stage(0, 0);
    __syncthreads();
    int buf = 0;
    for (int ks = 0; ks < 10; ++ks) {
        if (ks < 9) stage(ks + 1, buf ^ 1);
        short8 af[4], bfr[4];
        #pragma unroll
        for (int fi = 0; fi < 4; ++fi)
            af[fi] = *(const short8*)&At[buf][qm * 64 + fi * 16 + r][8 * g];
        #pragma unroll
        for (int fj = 0; fj < 4; ++fj)
            bfr[fj] = *(const short8*)&Bt[buf][qn * 64 + fj * 16 + r][8 * g];
        #pragma unroll
        for (int fi = 0; fi < 4; ++fi)
            #pragma unroll
            for (int fj = 0; fj < 4; ++fj)
                acc[fi][fj] = __builtin_amdgcn_mfma_f32_16x16x32_bf16(af[fi], bfr[fj], acc[fi][fj], 0, 0, 0);
        __syncthreads();
        buf ^= 1;
    }

    ushort* qkp = qk + (size_t)p_l * (128 * MT) * NQK;
    ushort* vtp = vt + (size_t)p_l * BATCH * 15 * 20 * VS;
    #pragma unroll
    for (int fi = 0; fi < 4; ++fi) {
        #pragma unroll
        for (int fj = 0; fj < 4; ++fj) {
            int n = ntile * 128 + qn * 64 + fj * 16 + r;
            if (n < NQK) {
                #pragma unroll
                for (int j = 0; j < 4; ++j) {
                    int row = mtile * 128 + qm * 64 + fi * 16 + 4 * g + j;
                    qkp[(size_t)row * NQK + n] = f2bf(acc[fi][fj][j]);
                }
            } else if (n < 900) {
                int vj = n - 600;
                int h = vj / 20, jj = vj - h * 20;
                #pragma unroll
                for (int j = 0; j < 4; ++j) {
                    int row = mtile * 128 + qm * 64 + fi * 16 + 4 * g + j;
                    int b = row / LQ, l = row - b * LQ;
                    vtp[(((size_t)b * 15 + h) * 20 + jj) * VS + l] = f2bf(acc[fi][fj][j]);
                }
            }
        }
    }
}

// ---------- K3: attention -> ctx for L=30 (pure register, no LDS) ----------
__device__ __forceinline__ short8 load_qk_frag(const ushort* rowptr, int colbase, int g, bool rowvalid) {
    U32S8 v;
    v.s8 = (short8){0,0,0,0,0,0,0,0};
    if (rowvalid && g < 3) {
        const ushort* src = rowptr + colbase;
        if (g < 2) {
            v.h[0] = *(const short4v*)src;
            v.h[1] = *(const short4v*)(src + 4);
        } else {
            v.h[0] = *(const short4v*)src;
        }
    }
    return v.s8;
}

__global__ __launch_bounds__(256)
void attn_ctx(const ushort* __restrict__ qk,   // [P_chunk][3840][600]
              const ushort* __restrict__ vt,   // [P_chunk][128][15][640]
              ushort* __restrict__ ctx,        // [P_chunk][128][32][320]
              int)
{
    const int tid  = threadIdx.x;
    const int wave = tid >> 6;
    const int lane = tid & 63;
    const int r = lane & 15, g = lane >> 4;
    const int p_l = blockIdx.x / BATCH;
    const int b   = blockIdx.x % BATCH;

    const ushort* qb  = qk + ((size_t)p_l * BATCH + b) * 30 * NQK;
    const ushort* vb  = vt + ((size_t)p_l * BATCH + b) * 15 * 640;
    ushort* cb = ctx + ((size_t)p_l * BATCH + b) * 32 * CTS;

    for (int i = tid; i < 2 * CTS; i += 256) cb[30 * CTS + i] = 0;
    for (int i = tid; i < 32 * 20; i += 256) {
        int row = i / 20, c = 300 + i % 20;
        cb[row * CTS + c] = 0;
    }

    for (int hp = 0; hp < 4; ++hp) {
        int head = wave + 4 * hp;
        if (head < 15) {
            short8 q0 = load_qk_frag(qb + (size_t)(r) * NQK,      head * 20 + 8 * g, g, r < 30);
            short8 q1 = load_qk_frag(qb + (size_t)(16 + r) * NQK, head * 20 + 8 * g, g, 16 + r < 30);
            short8 k0 = load_qk_frag(qb + (size_t)(r) * NQK,      300 + head * 20 + 8 * g, g, r < 30);
            short8 k1 = load_qk_frag(qb + (size_t)(16 + r) * NQK, 300 + head * 20 + 8 * g, g, 16 + r < 30);
            short8 vf0 = *(const short8*)&vb[head * 640 + r * 32 + 8 * g];
            short8 vf1 = (16 + r < 20) ? *(const short8*)&vb[head * 640 + (16 + r) * 32 + 8 * g]
                                       : (short8){0,0,0,0,0,0,0,0};

            f32x4 s0m0 = {0,0,0,0}, s0m1 = {0,0,0,0}, s1m0 = {0,0,0,0}, s1m1 = {0,0,0,0};
            s0m0 = __builtin_amdgcn_mfma_f32_16x16x32_bf16(k0, q0, s0m0, 0, 0, 0);
            s0m1 = __builtin_amdgcn_mfma_f32_16x16x32_bf16(k1, q0, s0m1, 0, 0, 0);
            s1m0 = __builtin_amdgcn_mfma_f32_16x16x32_bf16(k0, q1, s1m0, 0, 0, 0);
            s1m1 = __builtin_amdgcn_mfma_f32_16x16x32_bf16(k1, q1, s1m1, 0, 0, 0);

            float mx0 = -1e30f, mx1 = -1e30f;
            #pragma unroll
            for (int j = 0; j < 4; ++j) {
                s0m0[j] *= SCALE; s1m0[j] *= SCALE;
                float v01 = (16 + 4 * g + j < 30) ? s0m1[j] * SCALE : -1e30f;
                float v11 = (16 + 4 * g + j < 30) ? s1m1[j] * SCALE : -1e30f;
                s0m1[j] = v01; s1m1[j] = v11;
                mx0 = fmaxf(mx0, fmaxf(s0m0[j], v01));
                mx1 = fmaxf(mx1, fmaxf(s1m0[j], v11));
            }
            mx0 = fmaxf(mx0, __shfl_xor(mx0, 16, 64));
            mx0 = fmaxf(mx0, __shfl_xor(mx0, 32, 64));
            mx1 = fmaxf(mx1, __shfl_xor(mx1, 16, 64));
            mx1 = fmaxf(mx1, __shfl_xor(mx1, 32, 64));
            float sm0 = 0.f, sm1 = 0.f;
            #pragma unroll
            for (int j = 0; j < 4; ++j) {
                s0m0[j] = __expf(s0m0[j] - mx0); s0m1[j] = __expf(s0m1[j] - mx0);
                s1m0[j] = __expf(s1m0[j] - mx1); s1m1[j] = __expf(s1m1[j] - mx1);
                sm0 += s0m0[j] + s0m1[j];
                sm1 += s1m0[j] + s1m1[j];
            }
            sm0 += __shfl_xor(sm0, 16, 64); sm0 += __shfl_xor(sm0, 32, 64);
            sm1 += __shfl_xor(sm1, 16, 64); sm1 += __shfl_xor(sm1, 32, 64);
            float inv0 = 1.0f / sm0, inv1 = 1.0f / sm1;

            unsigned pk000 = pack2bf(s0m0[0] * inv0, s0m0[1] * inv0);
            unsigned pk001 = pack2bf(s0m0[2] * inv0, s0m0[3] * inv0);
            unsigned pk010 = pack2bf(s0m1[0] * inv0, s0m1[1] * inv0);
            unsigned pk011 = pack2bf(s0m1[2] * inv0, s0m1[3] * inv0);
            unsigned pk100 = pack2bf(s1m0[0] * inv1, s1m0[1] * inv1);
            unsigned pk101 = pack2bf(s1m0[2] * inv1, s1m0[3] * inv1);
            unsigned pk110 = pack2bf(s1m1[0] * inv1, s1m1[1] * inv1);
            unsigned pk111 = pack2bf(s1m1[2] * inv1, s1m1[3] * inv1);

            const int sA = r + 16 * (2 * (g & 1));
            const int sB = sA + 16;
            const bool hi = (g >> 1) != 0;
            #pragma unroll
            for (int lt = 0; lt < 2; ++lt) {
                unsigned q00 = lt ? pk100 : pk000, q01 = lt ? pk101 : pk001;
                unsigned q10 = lt ? pk110 : pk010, q11 = lt ? pk111 : pk011;
                unsigned a0 = __shfl((int)q00, sA, 64), a1 = __shfl((int)q01, sA, 64);
                unsigned a2 = __shfl((int)q10, sA, 64), a3 = __shfl((int)q11, sA, 64);
                unsigned b0 = __shfl((int)q00, sB, 64), b1 = __shfl((int)q01, sB, 64);
                unsigned b2 = __shfl((int)q10, sB, 64), b3 = __shfl((int)q11, sB, 64);
                U32S8 pf;
                pf.u[0] = hi ? a2 : a0;
                pf.u[1] = hi ? a3 : a1;
                pf.u[2] = hi ? b2 : b0;
                pf.u[3] = hi ? b3 : b1;
                int lrow = lt * 16 + r;
                #pragma unroll
                for (int nt = 0; nt < 2; ++nt) {
                    short8 vf = nt ? vf1 : vf0;
                    f32x4 c = {0.f, 0.f, 0.f, 0.f};
                    c = __builtin_amdgcn_mfma_f32_16x16x32_bf16(vf, pf.s8, c, 0, 0, 0);
                    if (lrow < 30) {
                        #pragma unroll
                        for (int j = 0; j < 4; ++j) {
                            int vj = nt * 16 + 4 * g + j;
                            if (vj < 20)
                                cb[lrow * CTS + head * 20 + vj] = f2bf(c[j]);
                        }
                    }
                }
            }
        }
    }
}

// ---------- K3b: attention -> ctx for L=50 (user), LDS P staging ----------
__global__ __launch_bounds__(512, 1)
void attn50(const ushort* __restrict__ qk,   // [6464][600]
            const ushort* __restrict__ vt,   // [128][15][20][64]
            ushort* __restrict__ ctx)        // [128][64][320]
{
    __shared__ ushort P_l[8][64 * 68];   // per-wave P tile, stride 68

    const int tid  = threadIdx.x;
    const int wave = tid >> 6;
    const int lane = tid & 63;
    const int r = lane & 15, g = lane >> 4;
    const int b = blockIdx.x;

    const ushort* qb = qk + (size_t)b * 50 * NQK;
    ushort* pw = &P_l[wave][0];

    for (int hh = wave; hh < 15; hh += 8) {
        // Q, K fragments (4 row-tiles each; pad rows are garbage -> discarded/masked)
        short8 qf[4], kf[4];
        #pragma unroll
        for (int t4 = 0; t4 < 4; ++t4) {
            qf[t4] = load_qk_frag(qb + (size_t)(t4 * 16 + r) * NQK, hh * 20 + 8 * g, g, true);
            kf[t4] = load_qk_frag(qb + (size_t)(t4 * 16 + r) * NQK, 300 + hh * 20 + 8 * g, g, true);
        }
        // V^T fragments
        short8 vf[2][2];
        #pragma unroll
        for (int nt = 0; nt < 2; ++nt) {
            int vj = nt * 16 + r;
            #pragma unroll
            for (int ks = 0; ks < 2; ++ks) {
                if (vj < 20)
                    vf[nt][ks] = *(const short8*)&vt[(((size_t)b * 15 + hh) * 20 + vj) * 64 + ks * 32 + 8 * g];
                else
                    vf[nt][ks] = (short8){0,0,0,0,0,0,0,0};
            }
        }

        // S: lane reg j = S[l=qt*16+r][m=kt*16+4g+j]
        f32x4 s[4][4];
        #pragma unroll
        for (int qt = 0; qt < 4; ++qt)
            #pragma unroll
            for (int kt = 0; kt < 4; ++kt) {
                f32x4 z = {0.f, 0.f, 0.f, 0.f};
                s[qt][kt] = __builtin_amdgcn_mfma_f32_16x16x32_bf16(kf[kt], qf[qt], z, 0, 0, 0);
            }

        // scale + mask cols >= 50, row softmax
        float mx[4], sm[4];
        #pragma unroll
        for (int qt = 0; qt < 4; ++qt) {
            float m = -1e30f;
            #pragma unroll
            for (int kt = 0; kt < 4; ++kt)
                #pragma unroll
                for (int j = 0; j < 4; ++j) {
                    int col = kt * 16 + 4 * g + j;
                    float v = (col < 50) ? s[qt][kt][j] * SCALE : -1e30f;
                    s[qt][kt][j] = v;
                    m = fmaxf(m, v);
                }
            m = fmaxf(m, __shfl_xor(m, 16, 64));
            m = fmaxf(m, __shfl_xor(m, 32, 64));
            mx[qt] = m;
            float sum = 0.f;
            #pragma unroll
            for (int kt = 0; kt < 4; ++kt)
                #pragma unroll
                for (int j = 0; j < 4; ++j) {
                    float e = __expf(s[qt][kt][j] - m);
                    s[qt][kt][j] = e;
                    sum += e;
                }
            sum += __shfl_xor(sum, 16, 64);
            sum += __shfl_xor(sum, 32, 64);
            sm[qt] = 1.0f / sum;
        }

        // write P to LDS: P[l][m], row stride 68
        #pragma unroll
        for (int qt = 0; qt < 4; ++qt) {
            float inv = sm[qt];
            #pragma unroll
            for (int kt = 0; kt < 4; ++kt) {
                unsigned w0 = pack2bf(s[qt][kt][0] * inv, s[qt][kt][1] * inv);
                unsigned w1 = pack2bf(s[qt][kt][2] * inv, s[qt][kt][3] * inv);
                ushort* dst = pw + (qt * 16 + r) * 68 + kt * 16 + 4 * g;
                *(unsigned*)dst = w0;
                *(unsigned*)(dst + 2) = w1;
            }
        }
        asm volatile("s_waitcnt lgkmcnt(0)");
        __builtin_amdgcn_sched_barrier(0);

        // PV: ctx^T[vj][l] = V^T x P^T (B-frag = contiguous P rows)
        #pragma unroll
        for (int lt = 0; lt < 4; ++lt) {
            short8 pf0 = *(const short8*)(pw + (lt * 16 + r) * 68 + 8 * g);
            short8 pf1 = *(const short8*)(pw + (lt * 16 + r) * 68 + 32 + 8 * g);
            int l = lt * 16 + r;
            #pragma unroll
            for (int nt = 0; nt < 2; ++nt) {
                f32x4 c = {0.f, 0.f, 0.f, 0.f};
                c = __builtin_amdgcn_mfma_f32_16x16x32_bf16(vf[nt][0], pf0, c, 0, 0, 0);
                c = __builtin_amdgcn_mfma_f32_16x16x32_bf16(vf[nt][1], pf1, c, 0, 0, 0);
                int vjb = nt * 16 + 4 * g;
                if (l < 50 && vjb < 17) {
                    unsigned w0 = pack2bf(c[0], c[1]);
                    unsigned w1 = pack2bf(c[2], c[3]);
                    ushort* d = ctx + ((size_t)b * 64 + l) * CTS + hh * 20 + vjb;
                    *(unsigned*)d = w0;
                    *(unsigned*)(d + 2) = w1;
                }
            }
        }
    }
}

// ---------- K4: pooling GEMM (news/cand): 4 x 32-row instances per block ----------
__global__ __launch_bounds__(256, 2)
void pool_gemm(const ushort* __restrict__ ctx,   // [P_chunk][128][32][320]
               const ushort* __restrict__ wt_wp, // [P_all][208][320]
               const float* __restrict__ bp, const float* __restrict__ qv,
               float* __restrict__ out,          // [B][P_all][300]
               int p0, int P_all)
{
    __shared__ ushort Bt[2][208 * 40];
    __shared__ float  logit[128];
    __shared__ float  aw[128];

    const int tid  = threadIdx.x;
    const int wave = tid >> 6;
    const int lane = tid & 63;
    const int r = lane & 15, g = lane >> 4;
    const int p_l   = blockIdx.x >> 5;
    const int mtile = blockIdx.x & 31;
    const int p_g   = p0 + p_l;

    const ushort* cbase = ctx + (size_t)p_l * BATCH * 32 * CTS + (size_t)mtile * 128 * CTS;
    const ushort* wpp = wt_wp + (size_t)p_g * NWP * KP;

    auto stageB = [&](int ks, int buf) {
        for (int i = tid; i < 832; i += 256) {
            int n = i >> 2, kk = (i & 3) * 8;
            *(short8*)&Bt[buf][n * 40 + kk] = *(const short8*)&wpp[(size_t)n * KP + ks * 32 + kk];
        }
    };

    float bpr[13], qvr[13];
    #pragma unroll
    for (int nf = 0; nf < 13; ++nf) {
        int col = nf * 16 + r;
        bpr[nf] = (col < 200) ? bp[p_g * 200 + col] : 0.f;
        qvr[nf] = (col < 200) ? qv[p_g * 200 + col] : 0.f;
    }

    f32x4 acc[2][13];
    #pragma unroll
    for (int mf = 0; mf < 2; ++mf)
        #pragma unroll
        for (int nf = 0; nf < 13; ++nf)
            acc[mf][nf] = (f32x4){0.f, 0.f, 0.f, 0.f};

    stageB(0, 0);
    __syncthreads();
    int buf = 0;
    for (int ks = 0; ks < 10; ++ks) {
        if (ks < 9) stageB(ks + 1, buf ^ 1);
        short8 af[2];
        #pragma unroll
        for (int mf = 0; mf < 2; ++mf)
            af[mf] = *(const short8*)&cbase[(size_t)(wave * 32 + mf * 16 + r) * CTS + ks * 32 + 8 * g];
        #pragma unroll
        for (int mf = 0; mf < 2; ++mf)
            #pragma unroll
            for (int nf = 0; nf < 13; ++nf) {
                short8 bf = *(const short8*)&Bt[buf][(nf * 16 + r) * 40 + 8 * g];
                acc[mf][nf] = __builtin_amdgcn_mfma_f32_16x16x32_bf16(af[mf], bf, acc[mf][nf], 0, 0, 0);
            }
        __syncthreads();
        buf ^= 1;
    }

    #pragma unroll
    for (int mf = 0; mf < 2; ++mf) {
        #pragma unroll
        for (int j = 0; j < 4; ++j) {
            float s = 0.f;
            #pragma unroll
            for (int nf = 0; nf < 13; ++nf)
                s += tanhf(acc[mf][nf][j] + bpr[nf]) * qvr[nf];
            s += __shfl_xor(s, 1, 64);
            s += __shfl_xor(s, 2, 64);
            s += __shfl_xor(s, 4, 64);
            s += __shfl_xor(s, 8, 64);
            if (r == 0) logit[wave * 32 + mf * 16 + 4 * g + j] = s;
        }
    }
    __syncthreads();

    {
        float x = (lane < 30) ? logit[wave * 32 + lane] : -1e30f;
        float mx = x;
        #pragma unroll
        for (int off = 1; off < 64; off <<= 1) mx = fmaxf(mx, __shfl_xor(mx, off, 64));
        float e = (lane < 30) ? __expf(x - mx) : 0.f;
        float sm = e;
        #pragma unroll
        for (int off = 1; off < 64; off <<= 1) sm += __shfl_xor(sm, off, 64);
        if (lane < 32) aw[wave * 32 + lane] = e / sm;
    }
    __syncthreads();

    for (int idx = tid; idx < 4 * 300; idx += 256) {
        int inst = idx / 300, c = idx - inst * 300;
        const ushort* crow = cbase + (size_t)inst * 32 * CTS + c;
        float o = 0.f;
        #pragma unroll
        for (int l = 0; l < 30; ++l)
            o = fmaf(aw[inst * 32 + l], bf2f(crow[(size_t)l * CTS]), o);
        int b = mtile * 4 + inst;
        out[((size_t)b * P_all + p_g) * 300 + c] = o;
    }
}

// ---------- K4b: pooling for user (2 x 64-row instances per block) ----------
__global__ __launch_bounds__(256, 2)
void pool50(const ushort* __restrict__ ctx,   // [128][64][320]
            const ushort* __restrict__ wt_wp, // [208][320]
            const float* __restrict__ bp, const float* __restrict__ qv,
            float* __restrict__ user_rep)     // [128][300]
{
    __shared__ ushort Bt[2][208 * 40];
    __shared__ float  logit[128];
    __shared__ float  aw[128];

    const int tid  = threadIdx.x;
    const int wave = tid >> 6;
    const int lane = tid & 63;
    const int r = lane & 15, g = lane >> 4;

    const ushort* cbase = ctx + (size_t)blockIdx.x * 2 * 64 * CTS;

    auto stageB = [&](int ks, int buf) {
        for (int i = tid; i < 832; i += 256) {
            int n = i >> 2, kk = (i & 3) * 8;
            *(short8*)&Bt[buf][n * 40 + kk] = *(const short8*)&wt_wp[(size_t)n * KP + ks * 32 + kk];
        }
    };

    float bpr[13], qvr[13];
    #pragma unroll
    for (int nf = 0; nf < 13; ++nf) {
        int col = nf * 16 + r;
        bpr[nf] = (col < 200) ? bp[col] : 0.f;
        qvr[nf] = (col < 200) ? qv[col] : 0.f;
    }

    f32x4 acc[2][13];
    #pragma unroll
    for (int mf = 0; mf < 2; ++mf)
        #pragma unroll
        for (int nf = 0; nf < 13; ++nf)
            acc[mf][nf] = (f32x4){0.f, 0.f, 0.f, 0.f};

    stageB(0, 0);
    __syncthreads();
    int buf = 0;
    for (int ks = 0; ks < 10; ++ks) {
        if (ks < 9) stageB(ks + 1, buf ^ 1);
        short8 af[2];
        #pragma unroll
        for (int mf = 0; mf < 2; ++mf)
            af[mf] = *(const short8*)&cbase[(size_t)(wave * 32 + mf * 16 + r) * CTS + ks * 32 + 8 * g];
        #pragma unroll
        for (int mf = 0; mf < 2; ++mf)
            #pragma unroll
            for (int nf = 0; nf < 13; ++nf) {
                short8 bf = *(const short8*)&Bt[buf][(nf * 16 + r) * 40 + 8 * g];
                acc[mf][nf] = __builtin_amdgcn_mfma_f32_16x16x32_bf16(af[mf], bf, acc[mf][nf], 0, 0, 0);
            }
        __syncthreads();
        buf ^= 1;
    }

    #pragma unroll
    for (int mf = 0; mf < 2; ++mf) {
        #pragma unroll
        for (int j = 0; j < 4; ++j) {
            float s = 0.f;
            #pragma unroll
            for (int nf = 0; nf < 13; ++nf)
                s += tanhf(acc[mf][nf][j] + bpr[nf]) * qvr[nf];
            s += __shfl_xor(s, 1, 64);
            s += __shfl_xor(s, 2, 64);
            s += __shfl_xor(s, 4, 64);
            s += __shfl_xor(s, 8, 64);
            if (r == 0) logit[wave * 32 + mf * 16 + 4 * g + j] = s;
        }
    }
    __syncthreads();

    // per-instance softmax over 64 rows (50 valid); waves 0,1 -> instances 0,1
    if (wave < 2) {
        float x = (lane < 50) ? logit[wave * 64 + lane] : -1e30f;
        float mx = x;
        #pragma unroll
        for (int off = 1; off < 64; off <<= 1) mx = fmaxf(mx, __shfl_xor(mx, off, 64));
        float e = (lane < 50) ? __expf(x - mx) : 0.f;
        float sm = e;
        #pragma unroll
        for (int off = 1; off < 64; off <<= 1) sm += __shfl_xor(sm, off, 64);
        aw[wave * 64 + lane] = e / sm;
    }
    __syncthreads();

    for (int idx = tid; idx < 2 * 300; idx += 256) {
        int inst = idx / 300, c = idx - inst * 300;
        const ushort* crow = cbase + (size_t)inst * 64 * CTS + c;
        float o = 0.f;
        #pragma unroll
        for (int l = 0; l < 50; ++l)
            o = fmaf(aw[inst * 64 + l], bf2f(crow[(size_t)l * CTS]), o);
        int b = blockIdx.x * 2 + inst;
        user_rep[(size_t)b * 300 + c] = o;
    }
}

// ---------- final scoring ----------
__global__ __launch_bounds__(320)
void score_kernel(const float* __restrict__ user_rep, const float* __restrict__ cand_enc,
                  float* __restrict__ out)
{
    __shared__ float sc[NCAND];
    int b = blockIdx.x;
    int w = threadIdx.x >> 6;
    int lane = threadIdx.x & 63;
    float partial = 0.f;
    for (int d = lane; d < 300; d += 64)
        partial = fmaf(user_rep[b * 300 + d], cand_enc[((size_t)b * NCAND + w) * 300 + d], partial);
    for (int off = 32; off > 0; off >>= 1)
        partial += __shfl_down(partial, off, 64);
    if (lane == 0) sc[w] = partial;
    __syncthreads();
    if (threadIdx.x == 0) {
        float mx = -1e30f;
        for (int c = 0; c < NCAND; ++c) mx = fmaxf(mx, sc[c]);
        float s = 0.f; float e[NCAND];
        for (int c = 0; c < NCAND; ++c) { e[c] = __expf(sc[c] - mx); s += e[c]; }
        float inv = 1.0f / s;
        for (int c = 0; c < NCAND; ++c) out[b * NCAND + c] = e[c] * inv;
    }
}

extern "C" void kernel_launch(void* const* d_in, const int* in_sizes, int n_in,
                              void* d_out, int out_size, void* d_ws, size_t ws_size,
                              hipStream_t stream) {
    const int*   news_input = (const int*)d_in[0];
    const int*   candidates = (const int*)d_in[1];
    const float* emb        = (const float*)d_in[2];
    const float* his_Wq  = (const float*)d_in[3];
    const float* his_Wk  = (const float*)d_in[4];
    const float* his_Wv  = (const float*)d_in[5];
    const float* his_Wp  = (const float*)d_in[6];
    const float* his_bp  = (const float*)d_in[7];
    const float* his_qv  = (const float*)d_in[8];
    const float* cand_Wq = (const float*)d_in[9];
    const float* cand_Wk = (const float*)d_in[10];
    const float* cand_Wv = (const float*)d_in[11];
    const float* cand_Wp = (const float*)d_in[12];
    const float* cand_bp = (const float*)d_in[13];
    const float* cand_qv = (const float*)d_in[14];
    const float* usr_Wq  = (const float*)d_in[15];
    const float* usr_Wk  = (const float*)d_in[16];
    const float* usr_Wv  = (const float*)d_in[17];
    const float* usr_Wp  = (const float*)d_in[18];
    const float* usr_bp  = (const float*)d_in[19];
    const float* usr_qv  = (const float*)d_in[20];
    float* out = (float*)d_out;

    char* ws = (char*)d_ws;
    float* news_enc = (float*)ws;                 ws += (size_t)BATCH * NHIS * 300 * 4;
    float* cand_enc = (float*)ws;                 ws += (size_t)BATCH * NCAND * 300 * 4;
    float* user_rep = (float*)ws;                 ws += (size_t)BATCH * 300 * 4;
    ushort* his_qkvT  = (ushort*)ws;              ws += (size_t)NHIS * NQKV * KP * 2;
    ushort* his_wpT   = (ushort*)ws;              ws += (size_t)NHIS * NWP  * KP * 2;
    ushort* cand_qkvT = (ushort*)ws;              ws += (size_t)NCAND * NQKV * KP * 2;
    ushort* cand_wpT  = (ushort*)ws;              ws += (size_t)NCAND * NWP  * KP * 2;
    ushort* usr_qkvT  = (ushort*)ws;              ws += (size_t)NQKV * KP * 2;
    ushort* usr_wpT   = (ushort*)ws;              ws += (size_t)NWP  * KP * 2;

    size_t used = (size_t)(ws - (char*)d_ws);
    size_t avail = (ws_size > used) ? (ws_size - used) : 0;
    size_t qk_pp  = (size_t)3840 * NQK * 2;
    size_t vt_pp  = (size_t)BATCH * 15 * 640 * 2;
    size_t ctx_pp = (size_t)BATCH * 32 * CTS * 2;
    size_t per_p  = qk_pp + vt_pp + ctx_pp;
    int CP = 10;
    if (avail >= 50 * per_p) CP = 50;
    else if (avail >= 25 * per_p) CP = 25;

    ushort* qk_ws  = (ushort*)ws;
    ushort* vt_ws  = qk_ws + (size_t)CP * 3840 * NQK;
    ushort* ctx_ws = vt_ws + (size_t)CP * BATCH * 15 * 640;

    // user-pipeline buffers overlay the chunk region (user runs after news/cand)
    ushort* qk_u  = qk_ws;                          // [6464][600]
    ushort* vt_u  = qk_u + (size_t)6464 * NQK;      // [128][15][20][64]
    ushort* ctx_u = vt_u + (size_t)BATCH * 15 * 20 * 64;  // [128][64][320]

    auto blocks = [](size_t total) { return (int)((total + 255) / 256); };

    prep_qkv<<<blocks((size_t)NHIS  * NQKV * KP), 256, 0, stream>>>(his_Wq,  his_Wk,  his_Wv,  his_qkvT,  NHIS);
    prep_qkv<<<blocks((size_t)NCAND * NQKV * KP), 256, 0, stream>>>(cand_Wq, cand_Wk, cand_Wv, cand_qkvT, NCAND);
    prep_qkv<<<blocks((size_t)1     * NQKV * KP), 256, 0, stream>>>(usr_Wq,  usr_Wk,  usr_Wv,  usr_qkvT,  1);
    prep_wp <<<blocks((size_t)NHIS  * NWP  * KP), 256, 0, stream>>>(his_Wp,  his_wpT,  NHIS);
    prep_wp <<<blocks((size_t)NCAND * NWP  * KP), 256, 0, stream>>>(cand_Wp, cand_wpT, NCAND);
    prep_wp <<<blocks((size_t)1     * NWP  * KP), 256, 0, stream>>>(usr_Wp,  usr_wpT,  1);

    for (int p0 = 0; p0 < NHIS; p0 += CP) {
        int cp = (NHIS - p0 < CP) ? (NHIS - p0) : CP;
        qkv_gemm<30, true><<<cp * 240, 256, 0, stream>>>(emb, news_input, his_qkvT, qk_ws, vt_ws, p0, NHIS);
        attn_ctx<<<cp * BATCH, 256, 0, stream>>>(qk_ws, vt_ws, ctx_ws, 0);
        pool_gemm<<<cp * 32, 256, 0, stream>>>(ctx_ws, his_wpT, his_bp, his_qv, news_enc, p0, NHIS);
    }
    qkv_gemm<30, true><<<NCAND * 240, 256, 0, stream>>>(emb, candidates, cand_qkvT, qk_ws, vt_ws, 0, NCAND);
    attn_ctx<<<NCAND * BATCH, 256, 0, stream>>>(qk_ws, vt_ws, ctx_ws, 0);
    pool_gemm<<<NCAND * 32, 256, 0, stream>>>(ctx_ws, cand_wpT, cand_bp, cand_qv, cand_enc, 0, NCAND);

    // user encoder: split pipeline
    hipMemsetAsync(vt_u, 0, (size_t)BATCH * 15 * 20 * 64 * 2, stream);  // exact P=0 x 0 for m-pad
    qkv_gemm<50, false><<<400, 256, 0, stream>>>(news_enc, nullptr, usr_qkvT, qk_u, vt_u, 0, 1);
    attn50<<<BATCH, 512, 0, stream>>>(qk_u, vt_u, ctx_u);
    pool50<<<64, 256, 0, stream>>>(ctx_u, usr_wpT, usr_bp, usr_qv, user_rep);

    score_kernel<<<BATCH, 320, 0, stream>>>(user_rep, cand_enc, out);
}

// Round 7
// 1174.631 us; speedup vs baseline: 1.2702x; 1.1984x over previous
//
#include <hip/hip_runtime.h>
#include <math.h>

typedef __attribute__((ext_vector_type(8))) short short8;
typedef __attribute__((ext_vector_type(4))) short short4v;
typedef __attribute__((ext_vector_type(4))) float f32x4;

union U32S8 { unsigned u[4]; short8 s8; ushort e[8]; short4v h[2]; };

#define BATCH 128
#define NHIS  50
#define NCAND 5
#define KP    320   // padded K stride (elems) for weights, emb_bf, news_enc_bf
#define NQKV  912   // padded N for [Wq|Wk|Wv] weight buffer
#define NWP   208   // padded N for Wp
#define NQK   600   // Q|K row-major intermediate width
#define CTS   320   // ctx row stride (elems)
#define VOCAB 60000
#define SCALE 0.22360679774997896f  // 1/sqrt(20)

__device__ __forceinline__ ushort f2bf(float f) {
    union { float f; unsigned u; } v; v.f = f;
    return (ushort)((v.u + 0x7fffu + ((v.u >> 16) & 1u)) >> 16);
}
__device__ __forceinline__ unsigned pack2bf(float lo, float hi) {
    return (unsigned)f2bf(lo) | ((unsigned)f2bf(hi) << 16);
}
__device__ __forceinline__ float bf2f(ushort u) {
    union { float f; unsigned u; } v; v.u = ((unsigned)u) << 16;
    return v.f;
}

// ---------- prep: emb fp32 [V][300] -> bf16 [V][320] zero-padded ----------
__global__ void prep_emb(const float* __restrict__ emb, ushort* __restrict__ dst) {
    size_t gid = (size_t)blockIdx.x * 256 + threadIdx.x;
    size_t total8 = (size_t)VOCAB * (KP / 8);
    if (gid >= total8) return;
    size_t e0 = gid * 8;
    int row = (int)(e0 / KP);
    int c   = (int)(e0 - (size_t)row * KP);
    unsigned w[4] = {0, 0, 0, 0};
    if (c + 8 <= 300) {
        const float4* s = (const float4*)(emb + (size_t)row * 300 + c);
        float4 v0 = s[0], v1 = s[1];
        w[0] = pack2bf(v0.x, v0.y); w[1] = pack2bf(v0.z, v0.w);
        w[2] = pack2bf(v1.x, v1.y); w[3] = pack2bf(v1.z, v1.w);
    } else if (c < 300) {
        const float* s = emb + (size_t)row * 300;
        ushort tmp[8];
        #pragma unroll
        for (int i = 0; i < 8; ++i) tmp[i] = (c + i < 300) ? f2bf(s[c + i]) : (ushort)0;
        w[0] = tmp[0] | ((unsigned)tmp[1] << 16);
        w[1] = tmp[2] | ((unsigned)tmp[3] << 16);
        w[2] = tmp[4] | ((unsigned)tmp[5] << 16);
        w[3] = tmp[6] | ((unsigned)tmp[7] << 16);
    }
    *(unsigned*)(dst + e0)     = w[0];
    *(unsigned*)(dst + e0 + 2) = w[1];
    *(unsigned*)(dst + e0 + 4) = w[2];
    *(unsigned*)(dst + e0 + 6) = w[3];
}

// ---------- weight prep: W[k][n] fp32 -> WT[p][n][k] bf16, zero-padded ----------
__global__ void prep_qkv(const float* __restrict__ Wq, const float* __restrict__ Wk,
                         const float* __restrict__ Wv, ushort* __restrict__ dst, int P) {
    size_t i = (size_t)blockIdx.x * 256 + threadIdx.x;
    size_t total = (size_t)P * NQKV * KP;
    if (i >= total) return;
    int k = (int)(i % KP);
    int n = (int)((i / KP) % NQKV);
    int p = (int)(i / ((size_t)KP * NQKV));
    float v = 0.f;
    if (k < 300 && n < 900) {
        const float* W = (n < 300) ? Wq : (n < 600 ? Wk : Wv);
        int nn = n % 300;
        v = W[((size_t)p * 300 + k) * 300 + nn];
    }
    dst[i] = f2bf(v);
}

__global__ void prep_wp(const float* __restrict__ Wp, ushort* __restrict__ dst, int P) {
    size_t i = (size_t)blockIdx.x * 256 + threadIdx.x;
    size_t total = (size_t)P * NWP * KP;
    if (i >= total) return;
    int k = (int)(i % KP);
    int a = (int)((i / KP) % NWP);
    int p = (int)(i / ((size_t)KP * NWP));
    float v = 0.f;
    if (k < 300 && a < 200) v = Wp[((size_t)p * 300 + k) * 200 + a];
    dst[i] = f2bf(v);
}

// ---------- K2: batched QKV GEMM, bf16 source, XCD-aware bid remap ----------
// grid = 8 * S blocks; ntile = bid/S, idx = bid%S (S % 8 == 0 so all 8 ntiles
// sharing the same A-rows get identical bid%8 -> same XCD -> shared L2 A).
template<int LQ, bool GATHER>
__global__ __launch_bounds__(256, 4)
void qkv_gemm(const ushort* __restrict__ src_bf,  // GATHER: emb_bf [V][320]; else news_enc_bf [6400][320]
              const int* __restrict__ tokens,
              const ushort* __restrict__ wt,      // [P_all][NQKV][KP]
              ushort* __restrict__ qk, ushort* __restrict__ vt,
              int p0, int P_all, int S, int NPMT)
{
    constexpr int MT = (LQ == 30) ? 30 : 50;
    constexpr int VS = (LQ == 30) ? 32 : 64;

    __shared__ ushort At[2][128][40];
    __shared__ ushort Bt[2][128][40];
    __shared__ int TOK[128];

    const int bid   = blockIdx.x;
    const int ntile = bid / S;
    const int idx   = bid - ntile * S;
    if (idx >= NPMT) return;
    const int mtile = idx % MT;
    const int p_l   = idx / MT;
    const int p_g   = p0 + p_l;
    const int t     = threadIdx.x;
    const int wave  = t >> 6, lane = t & 63;
    const int r = lane & 15, g = lane >> 4;
    const int qm = wave >> 1, qn = wave & 1;

    if (GATHER && t < 128) {
        int row = mtile * 128 + t;
        int b = row / LQ, l = row - b * LQ;
        TOK[t] = tokens[((size_t)b * P_all + p_g) * LQ + l];
    }
    __syncthreads();

    const ushort* wtp = wt + (size_t)p_g * NQKV * KP;
    const int rr = t >> 1, half = t & 1;

    auto stage = [&](int ks, int buf) {
        {
            int base = ks * 32 + half * 16;
            const ushort* src;
            if (GATHER) src = src_bf + (size_t)TOK[rr] * KP + base;
            else        src = src_bf + (size_t)(mtile * 128 + rr) * KP + base;
            ushort* dst = &At[buf][rr][half * 16];
            ((short8*)dst)[0] = ((const short8*)src)[0];
            ((short8*)dst)[1] = ((const short8*)src)[1];
        }
        {
            int n = ntile * 128 + rr;
            ushort* dst = &Bt[buf][rr][half * 16];
            if (n < NQKV) {
                const ushort* srcb = wtp + (size_t)n * KP + ks * 32 + half * 16;
                ((short8*)dst)[0] = ((const short8*)srcb)[0];
                ((short8*)dst)[1] = ((const short8*)srcb)[1];
            } else {
                short8 z = {0,0,0,0,0,0,0,0};
                ((short8*)dst)[0] = z;
                ((short8*)dst)[1] = z;
            }
        }
    };

    f32x4 acc[4][4];
    #pragma unroll
    for (int i = 0; i < 4; ++i)
        #pragma unroll
        for (int j = 0; j < 4; ++j)
            acc[i][j] = (f32x4){0.f, 0.f, 0.f, 0.f};

    stage(0, 0);
    __syncthreads();
    int buf = 0;
    for (int ks = 0; ks < 10; ++ks) {
        if (ks < 9) stage(ks + 1, buf ^ 1);
        short8 af[4], bfr[4];
        #pragma unroll
        for (int fi = 0; fi < 4; ++fi)
            af[fi] = *(const short8*)&At[buf][qm * 64 + fi * 16 + r][8 * g];
        #pragma unroll
        for (int fj = 0; fj < 4; ++fj)
            bfr[fj] = *(const short8*)&Bt[buf][qn * 64 + fj * 16 + r][8 * g];
        #pragma unroll
        for (int fi = 0; fi < 4; ++fi)
            #pragma unroll
            for (int fj = 0; fj < 4; ++fj)
                acc[fi][fj] = __builtin_amdgcn_mfma_f32_16x16x32_bf16(af[fi], bfr[fj], acc[fi][fj], 0, 0, 0);
        __syncthreads();
        buf ^= 1;
    }

    ushort* qkp = qk + (size_t)p_l * (128 * MT) * NQK;
    ushort* vtp = vt + (size_t)p_l * BATCH * 15 * 20 * VS;
    #pragma unroll
    for (int fi = 0; fi < 4; ++fi) {
        #pragma unroll
        for (int fj = 0; fj < 4; ++fj) {
            int n = ntile * 128 + qn * 64 + fj * 16 + r;
            if (n < NQK) {
                #pragma unroll
                for (int j = 0; j < 4; ++j) {
                    int row = mtile * 128 + qm * 64 + fi * 16 + 4 * g + j;
                    qkp[(size_t)row * NQK + n] = f2bf(acc[fi][fj][j]);
                }
            } else if (n < 900) {
                int vj = n - 600;
                int h = vj / 20, jj = vj - h * 20;
                #pragma unroll
                for (int j = 0; j < 4; ++j) {
                    int row = mtile * 128 + qm * 64 + fi * 16 + 4 * g + j;
                    int b = row / LQ, l = row - b * LQ;
                    vtp[(((size_t)b * 15 + h) * 20 + jj) * VS + l] = f2bf(acc[fi][fj][j]);
                }
            }
        }
    }
}

// ---------- K3: attention -> ctx for L=30 (pure register, no LDS) ----------
__device__ __forceinline__ short8 load_qk_frag(const ushort* rowptr, int colbase, int g, bool rowvalid) {
    U32S8 v;
    v.s8 = (short8){0,0,0,0,0,0,0,0};
    if (rowvalid && g < 3) {
        const ushort* src = rowptr + colbase;
        if (g < 2) {
            v.h[0] = *(const short4v*)src;
            v.h[1] = *(const short4v*)(src + 4);
        } else {
            v.h[0] = *(const short4v*)src;
        }
    }
    return v.s8;
}

__global__ __launch_bounds__(256)
void attn_ctx(const ushort* __restrict__ qk,   // [P_chunk][3840][600]
              const ushort* __restrict__ vt,   // [P_chunk][128][15][640]
              ushort* __restrict__ ctx,        // [P_chunk][128][32][320]
              int)
{
    const int tid  = threadIdx.x;
    const int wave = tid >> 6;
    const int lane = tid & 63;
    const int r = lane & 15, g = lane >> 4;
    const int p_l = blockIdx.x / BATCH;
    const int b   = blockIdx.x % BATCH;

    const ushort* qb  = qk + ((size_t)p_l * BATCH + b) * 30 * NQK;
    const ushort* vb  = vt + ((size_t)p_l * BATCH + b) * 15 * 640;
    ushort* cb = ctx + ((size_t)p_l * BATCH + b) * 32 * CTS;

    for (int i = tid; i < 2 * CTS; i += 256) cb[30 * CTS + i] = 0;
    for (int i = tid; i < 32 * 20; i += 256) {
        int row = i / 20, c = 300 + i % 20;
        cb[row * CTS + c] = 0;
    }

    for (int hp = 0; hp < 4; ++hp) {
        int head = wave + 4 * hp;
        if (head < 15) {
            short8 q0 = load_qk_frag(qb + (size_t)(r) * NQK,      head * 20 + 8 * g, g, r < 30);
            short8 q1 = load_qk_frag(qb + (size_t)(16 + r) * NQK, head * 20 + 8 * g, g, 16 + r < 30);
            short8 k0 = load_qk_frag(qb + (size_t)(r) * NQK,      300 + head * 20 + 8 * g, g, r < 30);
            short8 k1 = load_qk_frag(qb + (size_t)(16 + r) * NQK, 300 + head * 20 + 8 * g, g, 16 + r < 30);
            short8 vf0 = *(const short8*)&vb[head * 640 + r * 32 + 8 * g];
            short8 vf1 = (16 + r < 20) ? *(const short8*)&vb[head * 640 + (16 + r) * 32 + 8 * g]
                                       : (short8){0,0,0,0,0,0,0,0};

            f32x4 s0m0 = {0,0,0,0}, s0m1 = {0,0,0,0}, s1m0 = {0,0,0,0}, s1m1 = {0,0,0,0};
            s0m0 = __builtin_amdgcn_mfma_f32_16x16x32_bf16(k0, q0, s0m0, 0, 0, 0);
            s0m1 = __builtin_amdgcn_mfma_f32_16x16x32_bf16(k1, q0, s0m1, 0, 0, 0);
            s1m0 = __builtin_amdgcn_mfma_f32_16x16x32_bf16(k0, q1, s1m0, 0, 0, 0);
            s1m1 = __builtin_amdgcn_mfma_f32_16x16x32_bf16(k1, q1, s1m1, 0, 0, 0);

            float mx0 = -1e30f, mx1 = -1e30f;
            #pragma unroll
            for (int j = 0; j < 4; ++j) {
                s0m0[j] *= SCALE; s1m0[j] *= SCALE;
                float v01 = (16 + 4 * g + j < 30) ? s0m1[j] * SCALE : -1e30f;
                float v11 = (16 + 4 * g + j < 30) ? s1m1[j] * SCALE : -1e30f;
                s0m1[j] = v01; s1m1[j] = v11;
                mx0 = fmaxf(mx0, fmaxf(s0m0[j], v01));
                mx1 = fmaxf(mx1, fmaxf(s1m0[j], v11));
            }
            mx0 = fmaxf(mx0, __shfl_xor(mx0, 16, 64));
            mx0 = fmaxf(mx0, __shfl_xor(mx0, 32, 64));
            mx1 = fmaxf(mx1, __shfl_xor(mx1, 16, 64));
            mx1 = fmaxf(mx1, __shfl_xor(mx1, 32, 64));
            float sm0 = 0.f, sm1 = 0.f;
            #pragma unroll
            for (int j = 0; j < 4; ++j) {
                s0m0[j] = __expf(s0m0[j] - mx0); s0m1[j] = __expf(s0m1[j] - mx0);
                s1m0[j] = __expf(s1m0[j] - mx1); s1m1[j] = __expf(s1m1[j] - mx1);
                sm0 += s0m0[j] + s0m1[j];
                sm1 += s1m0[j] + s1m1[j];
            }
            sm0 += __shfl_xor(sm0, 16, 64); sm0 += __shfl_xor(sm0, 32, 64);
            sm1 += __shfl_xor(sm1, 16, 64); sm1 += __shfl_xor(sm1, 32, 64);
            float inv0 = 1.0f / sm0, inv1 = 1.0f / sm1;

            unsigned pk000 = pack2bf(s0m0[0] * inv0, s0m0[1] * inv0);
            unsigned pk001 = pack2bf(s0m0[2] * inv0, s0m0[3] * inv0);
            unsigned pk010 = pack2bf(s0m1[0] * inv0, s0m1[1] * inv0);
            unsigned pk011 = pack2bf(s0m1[2] * inv0, s0m1[3] * inv0);
            unsigned pk100 = pack2bf(s1m0[0] * inv1, s1m0[1] * inv1);
            unsigned pk101 = pack2bf(s1m0[2] * inv1, s1m0[3] * inv1);
            unsigned pk110 = pack2bf(s1m1[0] * inv1, s1m1[1] * inv1);
            unsigned pk111 = pack2bf(s1m1[2] * inv1, s1m1[3] * inv1);

            const int sA = r + 16 * (2 * (g & 1));
            const int sB = sA + 16;
            const bool hi = (g >> 1) != 0;
            #pragma unroll
            for (int lt = 0; lt < 2; ++lt) {
                unsigned q00 = lt ? pk100 : pk000, q01 = lt ? pk101 : pk001;
                unsigned q10 = lt ? pk110 : pk010, q11 = lt ? pk111 : pk011;
                unsigned a0 = __shfl((int)q00, sA, 64), a1 = __shfl((int)q01, sA, 64);
                unsigned a2 = __shfl((int)q10, sA, 64), a3 = __shfl((int)q11, sA, 64);
                unsigned b0 = __shfl((int)q00, sB, 64), b1 = __shfl((int)q01, sB, 64);
                unsigned b2 = __shfl((int)q10, sB, 64), b3 = __shfl((int)q11, sB, 64);
                U32S8 pf;
                pf.u[0] = hi ? a2 : a0;
                pf.u[1] = hi ? a3 : a1;
                pf.u[2] = hi ? b2 : b0;
                pf.u[3] = hi ? b3 : b1;
                int lrow = lt * 16 + r;
                #pragma unroll
                for (int nt = 0; nt < 2; ++nt) {
                    short8 vf = nt ? vf1 : vf0;
                    f32x4 c = {0.f, 0.f, 0.f, 0.f};
                    c = __builtin_amdgcn_mfma_f32_16x16x32_bf16(vf, pf.s8, c, 0, 0, 0);
                    if (lrow < 30) {
                        #pragma unroll
                        for (int j = 0; j < 4; ++j) {
                            int vj = nt * 16 + 4 * g + j;
                            if (vj < 20)
                                cb[lrow * CTS + head * 20 + vj] = f2bf(c[j]);
                        }
                    }
                }
            }
        }
    }
}

// ---------- K3b: attention -> ctx for L=50 (user), LDS P staging ----------
__global__ __launch_bounds__(512, 1)
void attn50(const ushort* __restrict__ qk,   // [6464][600]
            const ushort* __restrict__ vt,   // [128][15][20][64]
            ushort* __restrict__ ctx)        // [128][64][320]
{
    __shared__ ushort P_l[8][64 * 68];

    const int tid  = threadIdx.x;
    const int wave = tid >> 6;
    const int lane = tid & 63;
    const int r = lane & 15, g = lane >> 4;
    const int b = blockIdx.x;

    const ushort* qb = qk + (size_t)b * 50 * NQK;
    ushort* pw = &P_l[wave][0];

    for (int hh = wave; hh < 15; hh += 8) {
        short8 qf[4], kf[4];
        #pragma unroll
        for (int t4 = 0; t4 < 4; ++t4) {
            qf[t4] = load_qk_frag(qb + (size_t)(t4 * 16 + r) * NQK, hh * 20 + 8 * g, g, true);
            kf[t4] = load_qk_frag(qb + (size_t)(t4 * 16 + r) * NQK, 300 + hh * 20 + 8 * g, g, true);
        }
        short8 vf[2][2];
        #pragma unroll
        for (int nt = 0; nt < 2; ++nt) {
            int vj = nt * 16 + r;
            #pragma unroll
            for (int ks = 0; ks < 2; ++ks) {
                if (vj < 20)
                    vf[nt][ks] = *(const short8*)&vt[(((size_t)b * 15 + hh) * 20 + vj) * 64 + ks * 32 + 8 * g];
                else
                    vf[nt][ks] = (short8){0,0,0,0,0,0,0,0};
            }
        }

        f32x4 s[4][4];
        #pragma unroll
        for (int qt = 0; qt < 4; ++qt)
            #pragma unroll
            for (int kt = 0; kt < 4; ++kt) {
                f32x4 z = {0.f, 0.f, 0.f, 0.f};
                s[qt][kt] = __builtin_amdgcn_mfma_f32_16x16x32_bf16(kf[kt], qf[qt], z, 0, 0, 0);
            }

        float mx[4], sm[4];
        #pragma unroll
        for (int qt = 0; qt < 4; ++qt) {
            float m = -1e30f;
            #pragma unroll
            for (int kt = 0; kt < 4; ++kt)
                #pragma unroll
                for (int j = 0; j < 4; ++j) {
                    int col = kt * 16 + 4 * g + j;
                    float v = (col < 50) ? s[qt][kt][j] * SCALE : -1e30f;
                    s[qt][kt][j] = v;
                    m = fmaxf(m, v);
                }
            m = fmaxf(m, __shfl_xor(m, 16, 64));
            m = fmaxf(m, __shfl_xor(m, 32, 64));
            mx[qt] = m;
            float sum = 0.f;
            #pragma unroll
            for (int kt = 0; kt < 4; ++kt)
                #pragma unroll
                for (int j = 0; j < 4; ++j) {
                    float e = __expf(s[qt][kt][j] - m);
                    s[qt][kt][j] = e;
                    sum += e;
                }
            sum += __shfl_xor(sum, 16, 64);
            sum += __shfl_xor(sum, 32, 64);
            sm[qt] = 1.0f / sum;
        }

        #pragma unroll
        for (int qt = 0; qt < 4; ++qt) {
            float inv = sm[qt];
            #pragma unroll
            for (int kt = 0; kt < 4; ++kt) {
                unsigned w0 = pack2bf(s[qt][kt][0] * inv, s[qt][kt][1] * inv);
                unsigned w1 = pack2bf(s[qt][kt][2] * inv, s[qt][kt][3] * inv);
                ushort* dst = pw + (qt * 16 + r) * 68 + kt * 16 + 4 * g;
                *(unsigned*)dst = w0;
                *(unsigned*)(dst + 2) = w1;
            }
        }
        asm volatile("s_waitcnt lgkmcnt(0)");
        __builtin_amdgcn_sched_barrier(0);

        #pragma unroll
        for (int lt = 0; lt < 4; ++lt) {
            short8 pf0 = *(const short8*)(pw + (lt * 16 + r) * 68 + 8 * g);
            short8 pf1 = *(const short8*)(pw + (lt * 16 + r) * 68 + 32 + 8 * g);
            int l = lt * 16 + r;
            #pragma unroll
            for (int nt = 0; nt < 2; ++nt) {
                f32x4 c = {0.f, 0.f, 0.f, 0.f};
                c = __builtin_amdgcn_mfma_f32_16x16x32_bf16(vf[nt][0], pf0, c, 0, 0, 0);
                c = __builtin_amdgcn_mfma_f32_16x16x32_bf16(vf[nt][1], pf1, c, 0, 0, 0);
                int vjb = nt * 16 + 4 * g;
                if (l < 50 && vjb < 17) {
                    unsigned w0 = pack2bf(c[0], c[1]);
                    unsigned w1 = pack2bf(c[2], c[3]);
                    ushort* d = ctx + ((size_t)b * 64 + l) * CTS + hh * 20 + vjb;
                    *(unsigned*)d = w0;
                    *(unsigned*)(d + 2) = w1;
                }
            }
        }
    }
}

// ---------- K4: pooling GEMM: 4 x 32-row instances per block ----------
// BF16OUT: write bf16 rows stride KP (news_enc_bf); else fp32 stride 300.
template<bool BF16OUT>
__global__ __launch_bounds__(256, 2)
void pool_gemm(const ushort* __restrict__ ctx,   // [P_chunk][128][32][320]
               const ushort* __restrict__ wt_wp, // [P_all][208][320]
               const float* __restrict__ bp, const float* __restrict__ qv,
               float* __restrict__ outf, ushort* __restrict__ outbf,
               int p0, int P_all)
{
    __shared__ ushort Bt[2][208 * 40];
    __shared__ float  logit[128];
    __shared__ float  aw[128];

    const int tid  = threadIdx.x;
    const int wave = tid >> 6;
    const int lane = tid & 63;
    const int r = lane & 15, g = lane >> 4;
    const int p_l   = blockIdx.x >> 5;
    const int mtile = blockIdx.x & 31;
    const int p_g   = p0 + p_l;

    const ushort* cbase = ctx + (size_t)p_l * BATCH * 32 * CTS + (size_t)mtile * 128 * CTS;
    const ushort* wpp = wt_wp + (size_t)p_g * NWP * KP;

    auto stageB = [&](int ks, int buf) {
        for (int i = tid; i < 832; i += 256) {
            int n = i >> 2, kk = (i & 3) * 8;
            *(short8*)&Bt[buf][n * 40 + kk] = *(const short8*)&wpp[(size_t)n * KP + ks * 32 + kk];
        }
    };

    float bpr[13], qvr[13];
    #pragma unroll
    for (int nf = 0; nf < 13; ++nf) {
        int col = nf * 16 + r;
        bpr[nf] = (col < 200) ? bp[p_g * 200 + col] : 0.f;
        qvr[nf] = (col < 200) ? qv[p_g * 200 + col] : 0.f;
    }

    f32x4 acc[2][13];
    #pragma unroll
    for (int mf = 0; mf < 2; ++mf)
        #pragma unroll
        for (int nf = 0; nf < 13; ++nf)
            acc[mf][nf] = (f32x4){0.f, 0.f, 0.f, 0.f};

    stageB(0, 0);
    __syncthreads();
    int buf = 0;
    for (int ks = 0; ks < 10; ++ks) {
        if (ks < 9) stageB(ks + 1, buf ^ 1);
        short8 af[2];
        #pragma unroll
        for (int mf = 0; mf < 2; ++mf)
            af[mf] = *(const short8*)&cbase[(size_t)(wave * 32 + mf * 16 + r) * CTS + ks * 32 + 8 * g];
        #pragma unroll
        for (int mf = 0; mf < 2; ++mf)
            #pragma unroll
            for (int nf = 0; nf < 13; ++nf) {
                short8 bf = *(const short8*)&Bt[buf][(nf * 16 + r) * 40 + 8 * g];
                acc[mf][nf] = __builtin_amdgcn_mfma_f32_16x16x32_bf16(af[mf], bf, acc[mf][nf], 0, 0, 0);
            }
        __syncthreads();
        buf ^= 1;
    }

    #pragma unroll
    for (int mf = 0; mf < 2; ++mf) {
        #pragma unroll
        for (int j = 0; j < 4; ++j) {
            float s = 0.f;
            #pragma unroll
            for (int nf = 0; nf < 13; ++nf)
                s += tanhf(acc[mf][nf][j] + bpr[nf]) * qvr[nf];
            s += __shfl_xor(s, 1, 64);
            s += __shfl_xor(s, 2, 64);
            s += __shfl_xor(s, 4, 64);
            s += __shfl_xor(s, 8, 64);
            if (r == 0) logit[wave * 32 + mf * 16 + 4 * g + j] = s;
        }
    }
    __syncthreads();

    {
        float x = (lane < 30) ? logit[wave * 32 + lane] : -1e30f;
        float mx = x;
        #pragma unroll
        for (int off = 1; off < 64; off <<= 1) mx = fmaxf(mx, __shfl_xor(mx, off, 64));
        float e = (lane < 30) ? __expf(x - mx) : 0.f;
        float sm = e;
        #pragma unroll
        for (int off = 1; off < 64; off <<= 1) sm += __shfl_xor(sm, off, 64);
        if (lane < 32) aw[wave * 32 + lane] = e / sm;
    }
    __syncthreads();

    for (int idx = tid; idx < 4 * 300; idx += 256) {
        int inst = idx / 300, c = idx - inst * 300;
        const ushort* crow = cbase + (size_t)inst * 32 * CTS + c;
        float o = 0.f;
        #pragma unroll
        for (int l = 0; l < 30; ++l)
            o = fmaf(aw[inst * 32 + l], bf2f(crow[(size_t)l * CTS]), o);
        int b = mtile * 4 + inst;
        if (BF16OUT) outbf[((size_t)b * P_all + p_g) * KP + c] = f2bf(o);
        else         outf[((size_t)b * P_all + p_g) * 300 + c] = o;
    }
}

// ---------- K4b: pooling for user (2 x 64-row instances per block) ----------
__global__ __launch_bounds__(256, 2)
void pool50(const ushort* __restrict__ ctx,   // [128][64][320]
            const ushort* __restrict__ wt_wp, // [208][320]
            const float* __restrict__ bp, const float* __restrict__ qv,
            float* __restrict__ user_rep)     // [128][300]
{
    __shared__ ushort Bt[2][208 * 40];
    __shared__ float  logit[128];
    __shared__ float  aw[128];

    const int tid  = threadIdx.x;
    const int wave = tid >> 6;
    const int lane = tid & 63;
    const int r = lane & 15, g = lane >> 4;

    const ushort* cbase = ctx + (size_t)blockIdx.x * 2 * 64 * CTS;

    auto stageB = [&](int ks, int buf) {
        for (int i = tid; i < 832; i += 256) {
            int n = i >> 2, kk = (i & 3) * 8;
            *(short8*)&Bt[buf][n * 40 + kk] = *(const short8*)&wt_wp[(size_t)n * KP + ks * 32 + kk];
        }
    };

    float bpr[13], qvr[13];
    #pragma unroll
    for (int nf = 0; nf < 13; ++nf) {
        int col = nf * 16 + r;
        bpr[nf] = (col < 200) ? bp[col] : 0.f;
        qvr[nf] = (col < 200) ? qv[col] : 0.f;
    }

    f32x4 acc[2][13];
    #pragma unroll
    for (int mf = 0; mf < 2; ++mf)
        #pragma unroll
        for (int nf = 0; nf < 13; ++nf)
            acc[mf][nf] = (f32x4){0.f, 0.f, 0.f, 0.f};

    stageB(0, 0);
    __syncthreads();
    int buf = 0;
    for (int ks = 0; ks < 10; ++ks) {
        if (ks < 9) stageB(ks + 1, buf ^ 1);
        short8 af[2];
        #pragma unroll
        for (int mf = 0; mf < 2; ++mf)
            af[mf] = *(const short8*)&cbase[(size_t)(wave * 32 + mf * 16 + r) * CTS + ks * 32 + 8 * g];
        #pragma unroll
        for (int mf = 0; mf < 2; ++mf)
            #pragma unroll
            for (int nf = 0; nf < 13; ++nf) {
                short8 bf = *(const short8*)&Bt[buf][(nf * 16 + r) * 40 + 8 * g];
                acc[mf][nf] = __builtin_amdgcn_mfma_f32_16x16x32_bf16(af[mf], bf, acc[mf][nf], 0, 0, 0);
            }
        __syncthreads();
        buf ^= 1;
    }

    #pragma unroll
    for (int mf = 0; mf < 2; ++mf) {
        #pragma unroll
        for (int j = 0; j < 4; ++j) {
            float s = 0.f;
            #pragma unroll
            for (int nf = 0; nf < 13; ++nf)
                s += tanhf(acc[mf][nf][j] + bpr[nf]) * qvr[nf];
            s += __shfl_xor(s, 1, 64);
            s += __shfl_xor(s, 2, 64);
            s += __shfl_xor(s, 4, 64);
            s += __shfl_xor(s, 8, 64);
            if (r == 0) logit[wave * 32 + mf * 16 + 4 * g + j] = s;
        }
    }
    __syncthreads();

    if (wave < 2) {
        float x = (lane < 50) ? logit[wave * 64 + lane] : -1e30f;
        float mx = x;
        #pragma unroll
        for (int off = 1; off < 64; off <<= 1) mx = fmaxf(mx, __shfl_xor(mx, off, 64));
        float e = (lane < 50) ? __expf(x - mx) : 0.f;
        float sm = e;
        #pragma unroll
        for (int off = 1; off < 64; off <<= 1) sm += __shfl_xor(sm, off, 64);
        aw[wave * 64 + lane] = e / sm;
    }
    __syncthreads();

    for (int idx = tid; idx < 2 * 300; idx += 256) {
        int inst = idx / 300, c = idx - inst * 300;
        const ushort* crow = cbase + (size_t)inst * 64 * CTS + c;
        float o = 0.f;
        #pragma unroll
        for (int l = 0; l < 50; ++l)
            o = fmaf(aw[inst * 64 + l], bf2f(crow[(size_t)l * CTS]), o);
        int b = blockIdx.x * 2 + inst;
        user_rep[(size_t)b * 300 + c] = o;
    }
}

// ---------- final scoring ----------
__global__ __launch_bounds__(320)
void score_kernel(const float* __restrict__ user_rep, const float* __restrict__ cand_enc,
                  float* __restrict__ out)
{
    __shared__ float sc[NCAND];
    int b = blockIdx.x;
    int w = threadIdx.x >> 6;
    int lane = threadIdx.x & 63;
    float partial = 0.f;
    for (int d = lane; d < 300; d += 64)
        partial = fmaf(user_rep[b * 300 + d], cand_enc[((size_t)b * NCAND + w) * 300 + d], partial);
    for (int off = 32; off > 0; off >>= 1)
        partial += __shfl_down(partial, off, 64);
    if (lane == 0) sc[w] = partial;
    __syncthreads();
    if (threadIdx.x == 0) {
        float mx = -1e30f;
        for (int c = 0; c < NCAND; ++c) mx = fmaxf(mx, sc[c]);
        float s = 0.f; float e[NCAND];
        for (int c = 0; c < NCAND; ++c) { e[c] = __expf(sc[c] - mx); s += e[c]; }
        float inv = 1.0f / s;
        for (int c = 0; c < NCAND; ++c) out[b * NCAND + c] = e[c] * inv;
    }
}

extern "C" void kernel_launch(void* const* d_in, const int* in_sizes, int n_in,
                              void* d_out, int out_size, void* d_ws, size_t ws_size,
                              hipStream_t stream) {
    const int*   news_input = (const int*)d_in[0];
    const int*   candidates = (const int*)d_in[1];
    const float* emb        = (const float*)d_in[2];
    const float* his_Wq  = (const float*)d_in[3];
    const float* his_Wk  = (const float*)d_in[4];
    const float* his_Wv  = (const float*)d_in[5];
    const float* his_Wp  = (const float*)d_in[6];
    const float* his_bp  = (const float*)d_in[7];
    const float* his_qv  = (const float*)d_in[8];
    const float* cand_Wq = (const float*)d_in[9];
    const float* cand_Wk = (const float*)d_in[10];
    const float* cand_Wv = (const float*)d_in[11];
    const float* cand_Wp = (const float*)d_in[12];
    const float* cand_bp = (const float*)d_in[13];
    const float* cand_qv = (const float*)d_in[14];
    const float* usr_Wq  = (const float*)d_in[15];
    const float* usr_Wk  = (const float*)d_in[16];
    const float* usr_Wv  = (const float*)d_in[17];
    const float* usr_Wp  = (const float*)d_in[18];
    const float* usr_bp  = (const float*)d_in[19];
    const float* usr_qv  = (const float*)d_in[20];
    float* out = (float*)d_out;

    char* ws = (char*)d_ws;
    ushort* emb_bf     = (ushort*)ws;             ws += (size_t)VOCAB * KP * 2;           // 38.4 MB
    ushort* news_enc_bf = (ushort*)ws;            ws += (size_t)BATCH * NHIS * KP * 2;    // 4.1 MB
    float* cand_enc = (float*)ws;                 ws += (size_t)BATCH * NCAND * 300 * 4;
    float* user_rep = (float*)ws;                 ws += (size_t)BATCH * 300 * 4;
    ushort* his_qkvT  = (ushort*)ws;              ws += (size_t)NHIS * NQKV * KP * 2;
    ushort* his_wpT   = (ushort*)ws;              ws += (size_t)NHIS * NWP  * KP * 2;
    ushort* cand_qkvT = (ushort*)ws;              ws += (size_t)NCAND * NQKV * KP * 2;
    ushort* cand_wpT  = (ushort*)ws;              ws += (size_t)NCAND * NWP  * KP * 2;
    ushort* usr_qkvT  = (ushort*)ws;              ws += (size_t)NQKV * KP * 2;
    ushort* usr_wpT   = (ushort*)ws;              ws += (size_t)NWP  * KP * 2;

    size_t used = (size_t)(ws - (char*)d_ws);
    size_t avail = (ws_size > used) ? (ws_size - used) : 0;
    size_t qk_pp  = (size_t)3840 * NQK * 2;
    size_t vt_pp  = (size_t)BATCH * 15 * 640 * 2;
    size_t ctx_pp = (size_t)BATCH * 32 * CTS * 2;
    size_t per_p  = qk_pp + vt_pp + ctx_pp;
    // user overlay needs ~26 MB; per_p ~9.7 MB -> CP>=3 guarantees space
    int CP = (int)(avail / per_p);
    if (CP > 50) CP = 50;
    if (CP < 3) CP = 3;

    ushort* qk_ws  = (ushort*)ws;
    ushort* vt_ws  = qk_ws + (size_t)CP * 3840 * NQK;
    ushort* ctx_ws = vt_ws + (size_t)CP * BATCH * 15 * 640;

    ushort* qk_u  = qk_ws;                                // [6464][600]
    ushort* vt_u  = qk_u + (size_t)6464 * NQK;            // [128][15][20][64]
    ushort* ctx_u = vt_u + (size_t)BATCH * 15 * 20 * 64;  // [128][64][320]

    auto blocks = [](size_t total) { return (int)((total + 255) / 256); };

    hipMemsetAsync(news_enc_bf, 0, (size_t)BATCH * NHIS * KP * 2, stream);  // zero col pads
    prep_emb<<<blocks((size_t)VOCAB * (KP / 8)), 256, 0, stream>>>(emb, emb_bf);
    prep_qkv<<<blocks((size_t)NHIS  * NQKV * KP), 256, 0, stream>>>(his_Wq,  his_Wk,  his_Wv,  his_qkvT,  NHIS);
    prep_qkv<<<blocks((size_t)NCAND * NQKV * KP), 256, 0, stream>>>(cand_Wq, cand_Wk, cand_Wv, cand_qkvT, NCAND);
    prep_qkv<<<blocks((size_t)1     * NQKV * KP), 256, 0, stream>>>(usr_Wq,  usr_Wk,  usr_Wv,  usr_qkvT,  1);
    prep_wp <<<blocks((size_t)NHIS  * NWP  * KP), 256, 0, stream>>>(his_Wp,  his_wpT,  NHIS);
    prep_wp <<<blocks((size_t)NCAND * NWP  * KP), 256, 0, stream>>>(cand_Wp, cand_wpT, NCAND);
    prep_wp <<<blocks((size_t)1     * NWP  * KP), 256, 0, stream>>>(usr_Wp,  usr_wpT,  1);

    for (int p0 = 0; p0 < NHIS; p0 += CP) {
        int cp = (NHIS - p0 < CP) ? (NHIS - p0) : CP;
        int npmt = cp * 30;
        int S = ((npmt + 7) / 8) * 8;
        qkv_gemm<30, true><<<8 * S, 256, 0, stream>>>(emb_bf, news_input, his_qkvT, qk_ws, vt_ws, p0, NHIS, S, npmt);
        attn_ctx<<<cp * BATCH, 256, 0, stream>>>(qk_ws, vt_ws, ctx_ws, 0);
        pool_gemm<true><<<cp * 32, 256, 0, stream>>>(ctx_ws, his_wpT, his_bp, his_qv, nullptr, news_enc_bf, p0, NHIS);
    }
    {
        int npmt = NCAND * 30;
        int S = ((npmt + 7) / 8) * 8;
        qkv_gemm<30, true><<<8 * S, 256, 0, stream>>>(emb_bf, candidates, cand_qkvT, qk_ws, vt_ws, 0, NCAND, S, npmt);
        attn_ctx<<<NCAND * BATCH, 256, 0, stream>>>(qk_ws, vt_ws, ctx_ws, 0);
        pool_gemm<false><<<NCAND * 32, 256, 0, stream>>>(ctx_ws, cand_wpT, cand_bp, cand_qv, cand_enc, nullptr, 0, NCAND);
    }

    // user encoder
    hipMemsetAsync(vt_u, 0, (size_t)BATCH * 15 * 20 * 64 * 2, stream);
    {
        int npmt = 50;
        int S = 56;
        qkv_gemm<50, false><<<8 * S, 256, 0, stream>>>(news_enc_bf, nullptr, usr_qkvT, qk_u, vt_u, 0, 1, S, npmt);
    }
    attn50<<<BATCH, 512, 0, stream>>>(qk_u, vt_u, ctx_u);
    pool50<<<64, 256, 0, stream>>>(ctx_u, usr_wpT, usr_bp, usr_qv, user_rep);

    score_kernel<<<BATCH, 320, 0, stream>>>(user_rep, cand_enc, out);
}

// Round 8
// 1159.616 us; speedup vs baseline: 1.2866x; 1.0129x over previous
//
#include <hip/hip_runtime.h>
#include <math.h>

typedef __attribute__((ext_vector_type(8))) short short8;
typedef __attribute__((ext_vector_type(4))) short short4v;
typedef __attribute__((ext_vector_type(4))) float f32x4;

union U32S8 { unsigned u[4]; short8 s8; ushort e[8]; short4v h[2]; };

#define BATCH 128
#define NHIS  50
#define NCAND 5
#define KP    320   // padded K stride (elems) for weights, emb_bf, news_enc_bf
#define NQKV  912   // padded N for [Wq|Wk|Wv] weight buffer
#define NWP   208   // padded N for Wp
#define NQK   600   // Q|K row-major intermediate width
#define CTS   320   // ctx row stride (elems)
#define VOCAB 60000
#define SCALE 0.22360679774997896f  // 1/sqrt(20)

__device__ __forceinline__ ushort f2bf(float f) {
    union { float f; unsigned u; } v; v.f = f;
    return (ushort)((v.u + 0x7fffu + ((v.u >> 16) & 1u)) >> 16);
}
__device__ __forceinline__ unsigned pack2bf(float lo, float hi) {
    return (unsigned)f2bf(lo) | ((unsigned)f2bf(hi) << 16);
}
__device__ __forceinline__ float bf2f(ushort u) {
    union { float f; unsigned u; } v; v.u = ((unsigned)u) << 16;
    return v.f;
}

// ---------- prep: emb fp32 [V][300] -> bf16 [V][320] zero-padded ----------
__global__ void prep_emb(const float* __restrict__ emb, ushort* __restrict__ dst) {
    size_t gid = (size_t)blockIdx.x * 256 + threadIdx.x;
    size_t total8 = (size_t)VOCAB * (KP / 8);
    if (gid >= total8) return;
    size_t e0 = gid * 8;
    int row = (int)(e0 / KP);
    int c   = (int)(e0 - (size_t)row * KP);
    unsigned w[4] = {0, 0, 0, 0};
    if (c + 8 <= 300) {
        const float4* s = (const float4*)(emb + (size_t)row * 300 + c);
        float4 v0 = s[0], v1 = s[1];
        w[0] = pack2bf(v0.x, v0.y); w[1] = pack2bf(v0.z, v0.w);
        w[2] = pack2bf(v1.x, v1.y); w[3] = pack2bf(v1.z, v1.w);
    } else if (c < 300) {
        const float* s = emb + (size_t)row * 300;
        ushort tmp[8];
        #pragma unroll
        for (int i = 0; i < 8; ++i) tmp[i] = (c + i < 300) ? f2bf(s[c + i]) : (ushort)0;
        w[0] = tmp[0] | ((unsigned)tmp[1] << 16);
        w[1] = tmp[2] | ((unsigned)tmp[3] << 16);
        w[2] = tmp[4] | ((unsigned)tmp[5] << 16);
        w[3] = tmp[6] | ((unsigned)tmp[7] << 16);
    }
    *(unsigned*)(dst + e0)     = w[0];
    *(unsigned*)(dst + e0 + 2) = w[1];
    *(unsigned*)(dst + e0 + 4) = w[2];
    *(unsigned*)(dst + e0 + 6) = w[3];
}

// ---------- weight prep: W[k][n] fp32 -> WT[p][n][k] bf16, zero-padded ----------
__global__ void prep_qkv(const float* __restrict__ Wq, const float* __restrict__ Wk,
                         const float* __restrict__ Wv, ushort* __restrict__ dst, int P) {
    size_t i = (size_t)blockIdx.x * 256 + threadIdx.x;
    size_t total = (size_t)P * NQKV * KP;
    if (i >= total) return;
    int k = (int)(i % KP);
    int n = (int)((i / KP) % NQKV);
    int p = (int)(i / ((size_t)KP * NQKV));
    float v = 0.f;
    if (k < 300 && n < 900) {
        const float* W = (n < 300) ? Wq : (n < 600 ? Wk : Wv);
        int nn = n % 300;
        v = W[((size_t)p * 300 + k) * 300 + nn];
    }
    dst[i] = f2bf(v);
}

__global__ void prep_wp(const float* __restrict__ Wp, ushort* __restrict__ dst, int P) {
    size_t i = (size_t)blockIdx.x * 256 + threadIdx.x;
    size_t total = (size_t)P * NWP * KP;
    if (i >= total) return;
    int k = (int)(i % KP);
    int a = (int)((i / KP) % NWP);
    int p = (int)(i / ((size_t)KP * NWP));
    float v = 0.f;
    if (k < 300 && a < 200) v = Wp[((size_t)p * 300 + k) * 200 + a];
    dst[i] = f2bf(v);
}

// ---------- K2: batched QKV GEMM, LDS-transposed coalesced epilogue ----------
template<int LQ, bool GATHER>
__global__ __launch_bounds__(256, 4)
void qkv_gemm(const ushort* __restrict__ src_bf,
              const int* __restrict__ tokens,
              const ushort* __restrict__ wt,      // [P_all][NQKV][KP]
              ushort* __restrict__ qk, ushort* __restrict__ vt,
              int p0, int P_all, int S, int NPMT)
{
    constexpr int MT = (LQ == 30) ? 30 : 50;
    constexpr int VS = (LQ == 30) ? 32 : 64;
    constexpr int TS = 136;   // transpose-tile row stride (272B, 16B-aligned rows)

    __shared__ ushort SMEM[20480];   // At | Bt during K-loop; T[128][136] in epilogue
    __shared__ int TOK[128];
    ushort (*At)[128][40] = (ushort (*)[128][40])(SMEM);
    ushort (*Bt)[128][40] = (ushort (*)[128][40])(SMEM + 10240);

    const int bid   = blockIdx.x;
    const int ntile = bid / S;
    const int idx   = bid - ntile * S;
    if (idx >= NPMT) return;
    const int mtile = idx % MT;
    const int p_l   = idx / MT;
    const int p_g   = p0 + p_l;
    const int t     = threadIdx.x;
    const int wave  = t >> 6, lane = t & 63;
    const int r = lane & 15, g = lane >> 4;
    const int qm = wave >> 1, qn = wave & 1;

    if (GATHER && t < 128) {
        int row = mtile * 128 + t;
        int b = row / LQ, l = row - b * LQ;
        TOK[t] = tokens[((size_t)b * P_all + p_g) * LQ + l];
    }
    __syncthreads();

    const ushort* wtp = wt + (size_t)p_g * NQKV * KP;
    const int rr = t >> 1, half = t & 1;

    auto stage = [&](int ks, int buf) {
        {
            int base = ks * 32 + half * 16;
            const ushort* src;
            if (GATHER) src = src_bf + (size_t)TOK[rr] * KP + base;
            else        src = src_bf + (size_t)(mtile * 128 + rr) * KP + base;
            ushort* dst = &At[buf][rr][half * 16];
            ((short8*)dst)[0] = ((const short8*)src)[0];
            ((short8*)dst)[1] = ((const short8*)src)[1];
        }
        {
            int n = ntile * 128 + rr;
            ushort* dst = &Bt[buf][rr][half * 16];
            if (n < NQKV) {
                const ushort* srcb = wtp + (size_t)n * KP + ks * 32 + half * 16;
                ((short8*)dst)[0] = ((const short8*)srcb)[0];
                ((short8*)dst)[1] = ((const short8*)srcb)[1];
            } else {
                short8 z = {0,0,0,0,0,0,0,0};
                ((short8*)dst)[0] = z;
                ((short8*)dst)[1] = z;
            }
        }
    };

    f32x4 acc[4][4];
    #pragma unroll
    for (int i = 0; i < 4; ++i)
        #pragma unroll
        for (int j = 0; j < 4; ++j)
            acc[i][j] = (f32x4){0.f, 0.f, 0.f, 0.f};

    stage(0, 0);
    __syncthreads();
    int buf = 0;
    for (int ks = 0; ks < 10; ++ks) {
        if (ks < 9) stage(ks + 1, buf ^ 1);
        short8 af[4], bfr[4];
        #pragma unroll
        for (int fi = 0; fi < 4; ++fi)
            af[fi] = *(const short8*)&At[buf][qm * 64 + fi * 16 + r][8 * g];
        #pragma unroll
        for (int fj = 0; fj < 4; ++fj)
            bfr[fj] = *(const short8*)&Bt[buf][qn * 64 + fj * 16 + r][8 * g];
        #pragma unroll
        for (int fi = 0; fi < 4; ++fi)
            #pragma unroll
            for (int fj = 0; fj < 4; ++fj)
                acc[fi][fj] = __builtin_amdgcn_mfma_f32_16x16x32_bf16(af[fi], bfr[fj], acc[fi][fj], 0, 0, 0);
        __syncthreads();
        buf ^= 1;
    }

    // ---- epilogue: acc -> LDS tile T[128][TS], then coalesced global writes ----
    ushort* T = SMEM;
    #pragma unroll
    for (int fi = 0; fi < 4; ++fi) {
        #pragma unroll
        for (int fj = 0; fj < 4; ++fj) {
            int col  = qn * 64 + fj * 16 + r;
            int rowb = qm * 64 + fi * 16 + 4 * g;
            #pragma unroll
            for (int j = 0; j < 4; ++j)
                T[(rowb + j) * TS + col] = f2bf(acc[fi][fj][j]);
        }
    }
    __syncthreads();

    const int R0 = mtile * 128;
    const int N0 = ntile * 128;
    ushort* qkp = qk + (size_t)p_l * (128 * MT) * NQK;
    ushort* vtp = vt + (size_t)p_l * BATCH * 15 * 20 * VS;

    // qk region: cols n in [N0, min(600, N0+128)) -- 16B LDS read -> 16B global store
    {
        int nqk = 600 - N0;
        if (nqk > 128) nqk = 128;
        if (nqk > 0) {
            int nch = nqk >> 3;   // always divisible (600%8==0, 128%8==0)
            for (int t2 = t; t2 < 128 * nch; t2 += 256) {
                int row = t2 / nch, cc = t2 - row * nch;
                short8 v = *(const short8*)&T[row * TS + cc * 8];
                *(short8*)&qkp[(size_t)(R0 + row) * NQK + N0 + cc * 8] = v;
            }
        }
    }
    // vt region: cols n in [max(600,N0), min(900, N0+128)) -> [b][h][jj][VS] l-runs
    {
        int c0 = 600 - N0; if (c0 < 0) c0 = 0;
        int c1 = 900 - N0; if (c1 > 128) c1 = 128;
        if (c1 > c0) {
            int nvt = c1 - c0;
            int b0 = R0 / LQ, b1 = (R0 + 127) / LQ;
            int nb = b1 - b0 + 1;
            for (int t2 = t; t2 < nvt * nb; t2 += 256) {
                int ci = t2 % nvt, bi = t2 / nvt;
                int c = c0 + ci;
                int vj = N0 + c - 600;
                int h = vj / 20, jj = vj - h * 20;
                int b = b0 + bi;
                int gr0 = b * LQ;      if (gr0 < R0) gr0 = R0;
                int gr1 = b * LQ + LQ; if (gr1 > R0 + 128) gr1 = R0 + 128;
                int l0 = gr0 - b * LQ, l1 = gr1 - b * LQ;
                ushort* dst = vtp + (((size_t)b * 15 + h) * 20 + jj) * VS;
                int l = l0;
                while (l < l1) {
                    if ((l & 7) == 0 && l + 8 <= l1) {
                        U32S8 v;
                        #pragma unroll
                        for (int i = 0; i < 8; ++i)
                            v.e[i] = T[(b * LQ + l + i - R0) * TS + c];
                        *(short8*)&dst[l] = v.s8;
                        l += 8;
                    } else if ((l & 1) == 0 && l + 2 <= l1) {
                        unsigned v = (unsigned)T[(b * LQ + l - R0) * TS + c] |
                                     ((unsigned)T[(b * LQ + l + 1 - R0) * TS + c] << 16);
                        *(unsigned*)&dst[l] = v;
                        l += 2;
                    } else {
                        dst[l] = T[(b * LQ + l - R0) * TS + c];
                        l += 1;
                    }
                }
            }
        }
    }
}

// ---------- K3: attention -> ctx for L=30 (pure register, no LDS) ----------
__device__ __forceinline__ short8 load_qk_frag(const ushort* rowptr, int colbase, int g, bool rowvalid) {
    U32S8 v;
    v.s8 = (short8){0,0,0,0,0,0,0,0};
    if (rowvalid && g < 3) {
        const ushort* src = rowptr + colbase;
        if (g < 2) {
            v.h[0] = *(const short4v*)src;
            v.h[1] = *(const short4v*)(src + 4);
        } else {
            v.h[0] = *(const short4v*)src;
        }
    }
    return v.s8;
}

__global__ __launch_bounds__(256)
void attn_ctx(const ushort* __restrict__ qk,   // [P_chunk][3840][600]
              const ushort* __restrict__ vt,   // [P_chunk][128][15][640]
              ushort* __restrict__ ctx,        // [P_chunk][128][32][320]
              int)
{
    const int tid  = threadIdx.x;
    const int wave = tid >> 6;
    const int lane = tid & 63;
    const int r = lane & 15, g = lane >> 4;
    const int p_l = blockIdx.x / BATCH;
    const int b   = blockIdx.x % BATCH;

    const ushort* qb  = qk + ((size_t)p_l * BATCH + b) * 30 * NQK;
    const ushort* vb  = vt + ((size_t)p_l * BATCH + b) * 15 * 640;
    ushort* cb = ctx + ((size_t)p_l * BATCH + b) * 32 * CTS;

    for (int i = tid; i < 2 * CTS; i += 256) cb[30 * CTS + i] = 0;
    for (int i = tid; i < 32 * 20; i += 256) {
        int row = i / 20, c = 300 + i % 20;
        cb[row * CTS + c] = 0;
    }

    for (int hp = 0; hp < 4; ++hp) {
        int head = wave + 4 * hp;
        if (head < 15) {
            short8 q0 = load_qk_frag(qb + (size_t)(r) * NQK,      head * 20 + 8 * g, g, r < 30);
            short8 q1 = load_qk_frag(qb + (size_t)(16 + r) * NQK, head * 20 + 8 * g, g, 16 + r < 30);
            short8 k0 = load_qk_frag(qb + (size_t)(r) * NQK,      300 + head * 20 + 8 * g, g, r < 30);
            short8 k1 = load_qk_frag(qb + (size_t)(16 + r) * NQK, 300 + head * 20 + 8 * g, g, 16 + r < 30);
            short8 vf0 = *(const short8*)&vb[head * 640 + r * 32 + 8 * g];
            short8 vf1 = (16 + r < 20) ? *(const short8*)&vb[head * 640 + (16 + r) * 32 + 8 * g]
                                       : (short8){0,0,0,0,0,0,0,0};

            f32x4 s0m0 = {0,0,0,0}, s0m1 = {0,0,0,0}, s1m0 = {0,0,0,0}, s1m1 = {0,0,0,0};
            s0m0 = __builtin_amdgcn_mfma_f32_16x16x32_bf16(k0, q0, s0m0, 0, 0, 0);
            s0m1 = __builtin_amdgcn_mfma_f32_16x16x32_bf16(k1, q0, s0m1, 0, 0, 0);
            s1m0 = __builtin_amdgcn_mfma_f32_16x16x32_bf16(k0, q1, s1m0, 0, 0, 0);
            s1m1 = __builtin_amdgcn_mfma_f32_16x16x32_bf16(k1, q1, s1m1, 0, 0, 0);

            float mx0 = -1e30f, mx1 = -1e30f;
            #pragma unroll
            for (int j = 0; j < 4; ++j) {
                s0m0[j] *= SCALE; s1m0[j] *= SCALE;
                float v01 = (16 + 4 * g + j < 30) ? s0m1[j] * SCALE : -1e30f;
                float v11 = (16 + 4 * g + j < 30) ? s1m1[j] * SCALE : -1e30f;
                s0m1[j] = v01; s1m1[j] = v11;
                mx0 = fmaxf(mx0, fmaxf(s0m0[j], v01));
                mx1 = fmaxf(mx1, fmaxf(s1m0[j], v11));
            }
            mx0 = fmaxf(mx0, __shfl_xor(mx0, 16, 64));
            mx0 = fmaxf(mx0, __shfl_xor(mx0, 32, 64));
            mx1 = fmaxf(mx1, __shfl_xor(mx1, 16, 64));
            mx1 = fmaxf(mx1, __shfl_xor(mx1, 32, 64));
            float sm0 = 0.f, sm1 = 0.f;
            #pragma unroll
            for (int j = 0; j < 4; ++j) {
                s0m0[j] = __expf(s0m0[j] - mx0); s0m1[j] = __expf(s0m1[j] - mx0);
                s1m0[j] = __expf(s1m0[j] - mx1); s1m1[j] = __expf(s1m1[j] - mx1);
                sm0 += s0m0[j] + s0m1[j];
                sm1 += s1m0[j] + s1m1[j];
            }
            sm0 += __shfl_xor(sm0, 16, 64); sm0 += __shfl_xor(sm0, 32, 64);
            sm1 += __shfl_xor(sm1, 16, 64); sm1 += __shfl_xor(sm1, 32, 64);
            float inv0 = 1.0f / sm0, inv1 = 1.0f / sm1;

            unsigned pk000 = pack2bf(s0m0[0] * inv0, s0m0[1] * inv0);
            unsigned pk001 = pack2bf(s0m0[2] * inv0, s0m0[3] * inv0);
            unsigned pk010 = pack2bf(s0m1[0] * inv0, s0m1[1] * inv0);
            unsigned pk011 = pack2bf(s0m1[2] * inv0, s0m1[3] * inv0);
            unsigned pk100 = pack2bf(s1m0[0] * inv1, s1m0[1] * inv1);
            unsigned pk101 = pack2bf(s1m0[2] * inv1, s1m0[3] * inv1);
            unsigned pk110 = pack2bf(s1m1[0] * inv1, s1m1[1] * inv1);
            unsigned pk111 = pack2bf(s1m1[2] * inv1, s1m1[3] * inv1);

            const int sA = r + 16 * (2 * (g & 1));
            const int sB = sA + 16;
            const bool hi = (g >> 1) != 0;
            #pragma unroll
            for (int lt = 0; lt < 2; ++lt) {
                unsigned q00 = lt ? pk100 : pk000, q01 = lt ? pk101 : pk001;
                unsigned q10 = lt ? pk110 : pk010, q11 = lt ? pk111 : pk011;
                unsigned a0 = __shfl((int)q00, sA, 64), a1 = __shfl((int)q01, sA, 64);
                unsigned a2 = __shfl((int)q10, sA, 64), a3 = __shfl((int)q11, sA, 64);
                unsigned b0 = __shfl((int)q00, sB, 64), b1 = __shfl((int)q01, sB, 64);
                unsigned b2 = __shfl((int)q10, sB, 64), b3 = __shfl((int)q11, sB, 64);
                U32S8 pf;
                pf.u[0] = hi ? a2 : a0;
                pf.u[1] = hi ? a3 : a1;
                pf.u[2] = hi ? b2 : b0;
                pf.u[3] = hi ? b3 : b1;
                int lrow = lt * 16 + r;
                #pragma unroll
                for (int nt = 0; nt < 2; ++nt) {
                    short8 vf = nt ? vf1 : vf0;
                    f32x4 c = {0.f, 0.f, 0.f, 0.f};
                    c = __builtin_amdgcn_mfma_f32_16x16x32_bf16(vf, pf.s8, c, 0, 0, 0);
                    if (lrow < 30) {
                        #pragma unroll
                        for (int j = 0; j < 4; ++j) {
                            int vj = nt * 16 + 4 * g + j;
                            if (vj < 20)
                                cb[lrow * CTS + head * 20 + vj] = f2bf(c[j]);
                        }
                    }
                }
            }
        }
    }
}

// ---------- K3b: attention -> ctx for L=50 (user), LDS P staging ----------
__global__ __launch_bounds__(512, 1)
void attn50(const ushort* __restrict__ qk,   // [6400][600]
            const ushort* __restrict__ vt,   // [128][15][20][64]
            ushort* __restrict__ ctx)        // [128][64][320]
{
    __shared__ ushort P_l[8][64 * 68];

    const int tid  = threadIdx.x;
    const int wave = tid >> 6;
    const int lane = tid & 63;
    const int r = lane & 15, g = lane >> 4;
    const int b = blockIdx.x;

    const ushort* qb = qk + (size_t)b * 50 * NQK;
    ushort* pw = &P_l[wave][0];

    for (int hh = wave; hh < 15; hh += 8) {
        short8 qf[4], kf[4];
        #pragma unroll
        for (int t4 = 0; t4 < 4; ++t4) {
            qf[t4] = load_qk_frag(qb + (size_t)(t4 * 16 + r) * NQK, hh * 20 + 8 * g, g, true);
            kf[t4] = load_qk_frag(qb + (size_t)(t4 * 16 + r) * NQK, 300 + hh * 20 + 8 * g, g, true);
        }
        short8 vf[2][2];
        #pragma unroll
        for (int nt = 0; nt < 2; ++nt) {
            int vj = nt * 16 + r;
            #pragma unroll
            for (int ks = 0; ks < 2; ++ks) {
                if (vj < 20)
                    vf[nt][ks] = *(const short8*)&vt[(((size_t)b * 15 + hh) * 20 + vj) * 64 + ks * 32 + 8 * g];
                else
                    vf[nt][ks] = (short8){0,0,0,0,0,0,0,0};
            }
        }

        f32x4 s[4][4];
        #pragma unroll
        for (int qt = 0; qt < 4; ++qt)
            #pragma unroll
            for (int kt = 0; kt < 4; ++kt) {
                f32x4 z = {0.f, 0.f, 0.f, 0.f};
                s[qt][kt] = __builtin_amdgcn_mfma_f32_16x16x32_bf16(kf[kt], qf[qt], z, 0, 0, 0);
            }

        float mx[4], sm[4];
        #pragma unroll
        for (int qt = 0; qt < 4; ++qt) {
            float m = -1e30f;
            #pragma unroll
            for (int kt = 0; kt < 4; ++kt)
                #pragma unroll
                for (int j = 0; j < 4; ++j) {
                    int col = kt * 16 + 4 * g + j;
                    float v = (col < 50) ? s[qt][kt][j] * SCALE : -1e30f;
                    s[qt][kt][j] = v;
                    m = fmaxf(m, v);
                }
            m = fmaxf(m, __shfl_xor(m, 16, 64));
            m = fmaxf(m, __shfl_xor(m, 32, 64));
            mx[qt] = m;
            float sum = 0.f;
            #pragma unroll
            for (int kt = 0; kt < 4; ++kt)
                #pragma unroll
                for (int j = 0; j < 4; ++j) {
                    float e = __expf(s[qt][kt][j] - m);
                    s[qt][kt][j] = e;
                    sum += e;
                }
            sum += __shfl_xor(sum, 16, 64);
            sum += __shfl_xor(sum, 32, 64);
            sm[qt] = 1.0f / sum;
        }

        #pragma unroll
        for (int qt = 0; qt < 4; ++qt) {
            float inv = sm[qt];
            #pragma unroll
            for (int kt = 0; kt < 4; ++kt) {
                unsigned w0 = pack2bf(s[qt][kt][0] * inv, s[qt][kt][1] * inv);
                unsigned w1 = pack2bf(s[qt][kt][2] * inv, s[qt][kt][3] * inv);
                ushort* dst = pw + (qt * 16 + r) * 68 + kt * 16 + 4 * g;
                *(unsigned*)dst = w0;
                *(unsigned*)(dst + 2) = w1;
            }
        }
        asm volatile("s_waitcnt lgkmcnt(0)");
        __builtin_amdgcn_sched_barrier(0);

        #pragma unroll
        for (int lt = 0; lt < 4; ++lt) {
            short8 pf0 = *(const short8*)(pw + (lt * 16 + r) * 68 + 8 * g);
            short8 pf1 = *(const short8*)(pw + (lt * 16 + r) * 68 + 32 + 8 * g);
            int l = lt * 16 + r;
            #pragma unroll
            for (int nt = 0; nt < 2; ++nt) {
                f32x4 c = {0.f, 0.f, 0.f, 0.f};
                c = __builtin_amdgcn_mfma_f32_16x16x32_bf16(vf[nt][0], pf0, c, 0, 0, 0);
                c = __builtin_amdgcn_mfma_f32_16x16x32_bf16(vf[nt][1], pf1, c, 0, 0, 0);
                int vjb = nt * 16 + 4 * g;
                if (l < 50 && vjb < 17) {
                    unsigned w0 = pack2bf(c[0], c[1]);
                    unsigned w1 = pack2bf(c[2], c[3]);
                    ushort* d = ctx + ((size_t)b * 64 + l) * CTS + hh * 20 + vjb;
                    *(unsigned*)d = w0;
                    *(unsigned*)(d + 2) = w1;
                }
            }
        }
    }
}

// ---------- K4: pooling GEMM: 4 x 32-row instances per block ----------
template<bool BF16OUT>
__global__ __launch_bounds__(256, 2)
void pool_gemm(const ushort* __restrict__ ctx,   // [P_chunk][128][32][320]
               const ushort* __restrict__ wt_wp, // [P_all][208][320]
               const float* __restrict__ bp, const float* __restrict__ qv,
               float* __restrict__ outf, ushort* __restrict__ outbf,
               int p0, int P_all)
{
    __shared__ ushort Bt[2][208 * 40];
    __shared__ float  logit[128];
    __shared__ float  aw[128];

    const int tid  = threadIdx.x;
    const int wave = tid >> 6;
    const int lane = tid & 63;
    const int r = lane & 15, g = lane >> 4;
    const int p_l   = blockIdx.x >> 5;
    const int mtile = blockIdx.x & 31;
    const int p_g   = p0 + p_l;

    const ushort* cbase = ctx + (size_t)p_l * BATCH * 32 * CTS + (size_t)mtile * 128 * CTS;
    const ushort* wpp = wt_wp + (size_t)p_g * NWP * KP;

    auto stageB = [&](int ks, int buf) {
        for (int i = tid; i < 832; i += 256) {
            int n = i >> 2, kk = (i & 3) * 8;
            *(short8*)&Bt[buf][n * 40 + kk] = *(const short8*)&wpp[(size_t)n * KP + ks * 32 + kk];
        }
    };

    float bpr[13], qvr[13];
    #pragma unroll
    for (int nf = 0; nf < 13; ++nf) {
        int col = nf * 16 + r;
        bpr[nf] = (col < 200) ? bp[p_g * 200 + col] : 0.f;
        qvr[nf] = (col < 200) ? qv[p_g * 200 + col] : 0.f;
    }

    f32x4 acc[2][13];
    #pragma unroll
    for (int mf = 0; mf < 2; ++mf)
        #pragma unroll
        for (int nf = 0; nf < 13; ++nf)
            acc[mf][nf] = (f32x4){0.f, 0.f, 0.f, 0.f};

    stageB(0, 0);
    __syncthreads();
    int buf = 0;
    for (int ks = 0; ks < 10; ++ks) {
        if (ks < 9) stageB(ks + 1, buf ^ 1);
        short8 af[2];
        #pragma unroll
        for (int mf = 0; mf < 2; ++mf)
            af[mf] = *(const short8*)&cbase[(size_t)(wave * 32 + mf * 16 + r) * CTS + ks * 32 + 8 * g];
        #pragma unroll
        for (int mf = 0; mf < 2; ++mf)
            #pragma unroll
            for (int nf = 0; nf < 13; ++nf) {
                short8 bf = *(const short8*)&Bt[buf][(nf * 16 + r) * 40 + 8 * g];
                acc[mf][nf] = __builtin_amdgcn_mfma_f32_16x16x32_bf16(af[mf], bf, acc[mf][nf], 0, 0, 0);
            }
        __syncthreads();
        buf ^= 1;
    }

    #pragma unroll
    for (int mf = 0; mf < 2; ++mf) {
        #pragma unroll
        for (int j = 0; j < 4; ++j) {
            float s = 0.f;
            #pragma unroll
            for (int nf = 0; nf < 13; ++nf)
                s += tanhf(acc[mf][nf][j] + bpr[nf]) * qvr[nf];
            s += __shfl_xor(s, 1, 64);
            s += __shfl_xor(s, 2, 64);
            s += __shfl_xor(s, 4, 64);
            s += __shfl_xor(s, 8, 64);
            if (r == 0) logit[wave * 32 + mf * 16 + 4 * g + j] = s;
        }
    }
    __syncthreads();

    {
        float x = (lane < 30) ? logit[wave * 32 + lane] : -1e30f;
        float mx = x;
        #pragma unroll
        for (int off = 1; off < 64; off <<= 1) mx = fmaxf(mx, __shfl_xor(mx, off, 64));
        float e = (lane < 30) ? __expf(x - mx) : 0.f;
        float sm = e;
        #pragma unroll
        for (int off = 1; off < 64; off <<= 1) sm += __shfl_xor(sm, off, 64);
        if (lane < 32) aw[wave * 32 + lane] = e / sm;
    }
    __syncthreads();

    for (int idx = tid; idx < 4 * 300; idx += 256) {
        int inst = idx / 300, c = idx - inst * 300;
        const ushort* crow = cbase + (size_t)inst * 32 * CTS + c;
        float o = 0.f;
        #pragma unroll
        for (int l = 0; l < 30; ++l)
            o = fmaf(aw[inst * 32 + l], bf2f(crow[(size_t)l * CTS]), o);
        int b = mtile * 4 + inst;
        if (BF16OUT) outbf[((size_t)b * P_all + p_g) * KP + c] = f2bf(o);
        else         outf[((size_t)b * P_all + p_g) * 300 + c] = o;
    }
}

// ---------- K4b: pooling for user (2 x 64-row instances per block) ----------
__global__ __launch_bounds__(256, 2)
void pool50(const ushort* __restrict__ ctx,   // [128][64][320]
            const ushort* __restrict__ wt_wp, // [208][320]
            const float* __restrict__ bp, const float* __restrict__ qv,
            float* __restrict__ user_rep)     // [128][300]
{
    __shared__ ushort Bt[2][208 * 40];
    __shared__ float  logit[128];
    __shared__ float  aw[128];

    const int tid  = threadIdx.x;
    const int wave = tid >> 6;
    const int lane = tid & 63;
    const int r = lane & 15, g = lane >> 4;

    const ushort* cbase = ctx + (size_t)blockIdx.x * 2 * 64 * CTS;

    auto stageB = [&](int ks, int buf) {
        for (int i = tid; i < 832; i += 256) {
            int n = i >> 2, kk = (i & 3) * 8;
            *(short8*)&Bt[buf][n * 40 + kk] = *(const short8*)&wt_wp[(size_t)n * KP + ks * 32 + kk];
        }
    };

    float bpr[13], qvr[13];
    #pragma unroll
    for (int nf = 0; nf < 13; ++nf) {
        int col = nf * 16 + r;
        bpr[nf] = (col < 200) ? bp[col] : 0.f;
        qvr[nf] = (col < 200) ? qv[col] : 0.f;
    }

    f32x4 acc[2][13];
    #pragma unroll
    for (int mf = 0; mf < 2; ++mf)
        #pragma unroll
        for (int nf = 0; nf < 13; ++nf)
            acc[mf][nf] = (f32x4){0.f, 0.f, 0.f, 0.f};

    stageB(0, 0);
    __syncthreads();
    int buf = 0;
    for (int ks = 0; ks < 10; ++ks) {
        if (ks < 9) stageB(ks + 1, buf ^ 1);
        short8 af[2];
        #pragma unroll
        for (int mf = 0; mf < 2; ++mf)
            af[mf] = *(const short8*)&cbase[(size_t)(wave * 32 + mf * 16 + r) * CTS + ks * 32 + 8 * g];
        #pragma unroll
        for (int mf = 0; mf < 2; ++mf)
            #pragma unroll
            for (int nf = 0; nf < 13; ++nf) {
                short8 bf = *(const short8*)&Bt[buf][(nf * 16 + r) * 40 + 8 * g];
                acc[mf][nf] = __builtin_amdgcn_mfma_f32_16x16x32_bf16(af[mf], bf, acc[mf][nf], 0, 0, 0);
            }
        __syncthreads();
        buf ^= 1;
    }

    #pragma unroll
    for (int mf = 0; mf < 2; ++mf) {
        #pragma unroll
        for (int j = 0; j < 4; ++j) {
            float s = 0.f;
            #pragma unroll
            for (int nf = 0; nf < 13; ++nf)
                s += tanhf(acc[mf][nf][j] + bpr[nf]) * qvr[nf];
            s += __shfl_xor(s, 1, 64);
            s += __shfl_xor(s, 2, 64);
            s += __shfl_xor(s, 4, 64);
            s += __shfl_xor(s, 8, 64);
            if (r == 0) logit[wave * 32 + mf * 16 + 4 * g + j] = s;
        }
    }
    __syncthreads();

    if (wave < 2) {
        float x = (lane < 50) ? logit[wave * 64 + lane] : -1e30f;
        float mx = x;
        #pragma unroll
        for (int off = 1; off < 64; off <<= 1) mx = fmaxf(mx, __shfl_xor(mx, off, 64));
        float e = (lane < 50) ? __expf(x - mx) : 0.f;
        float sm = e;
        #pragma unroll
        for (int off = 1; off < 64; off <<= 1) sm += __shfl_xor(sm, off, 64);
        aw[wave * 64 + lane] = e / sm;
    }
    __syncthreads();

    for (int idx = tid; idx < 2 * 300; idx += 256) {
        int inst = idx / 300, c = idx - inst * 300;
        const ushort* crow = cbase + (size_t)inst * 64 * CTS + c;
        float o = 0.f;
        #pragma unroll
        for (int l = 0; l < 50; ++l)
            o = fmaf(aw[inst * 64 + l], bf2f(crow[(size_t)l * CTS]), o);
        int b = blockIdx.x * 2 + inst;
        user_rep[(size_t)b * 300 + c] = o;
    }
}

// ---------- final scoring ----------
__global__ __launch_bounds__(320)
void score_kernel(const float* __restrict__ user_rep, const float* __restrict__ cand_enc,
                  float* __restrict__ out)
{
    __shared__ float sc[NCAND];
    int b = blockIdx.x;
    int w = threadIdx.x >> 6;
    int lane = threadIdx.x & 63;
    float partial = 0.f;
    for (int d = lane; d < 300; d += 64)
        partial = fmaf(user_rep[b * 300 + d], cand_enc[((size_t)b * NCAND + w) * 300 + d], partial);
    for (int off = 32; off > 0; off >>= 1)
        partial += __shfl_down(partial, off, 64);
    if (lane == 0) sc[w] = partial;
    __syncthreads();
    if (threadIdx.x == 0) {
        float mx = -1e30f;
        for (int c = 0; c < NCAND; ++c) mx = fmaxf(mx, sc[c]);
        float s = 0.f; float e[NCAND];
        for (int c = 0; c < NCAND; ++c) { e[c] = __expf(sc[c] - mx); s += e[c]; }
        float inv = 1.0f / s;
        for (int c = 0; c < NCAND; ++c) out[b * NCAND + c] = e[c] * inv;
    }
}

extern "C" void kernel_launch(void* const* d_in, const int* in_sizes, int n_in,
                              void* d_out, int out_size, void* d_ws, size_t ws_size,
                              hipStream_t stream) {
    const int*   news_input = (const int*)d_in[0];
    const int*   candidates = (const int*)d_in[1];
    const float* emb        = (const float*)d_in[2];
    const float* his_Wq  = (const float*)d_in[3];
    const float* his_Wk  = (const float*)d_in[4];
    const float* his_Wv  = (const float*)d_in[5];
    const float* his_Wp  = (const float*)d_in[6];
    const float* his_bp  = (const float*)d_in[7];
    const float* his_qv  = (const float*)d_in[8];
    const float* cand_Wq = (const float*)d_in[9];
    const float* cand_Wk = (const float*)d_in[10];
    const float* cand_Wv = (const float*)d_in[11];
    const float* cand_Wp = (const float*)d_in[12];
    const float* cand_bp = (const float*)d_in[13];
    const float* cand_qv = (const float*)d_in[14];
    const float* usr_Wq  = (const float*)d_in[15];
    const float* usr_Wk  = (const float*)d_in[16];
    const float* usr_Wv  = (const float*)d_in[17];
    const float* usr_Wp  = (const float*)d_in[18];
    const float* usr_bp  = (const float*)d_in[19];
    const float* usr_qv  = (const float*)d_in[20];
    float* out = (float*)d_out;

    char* ws = (char*)d_ws;
    ushort* emb_bf     = (ushort*)ws;             ws += (size_t)VOCAB * KP * 2;           // 38.4 MB
    ushort* news_enc_bf = (ushort*)ws;            ws += (size_t)BATCH * NHIS * KP * 2;    // 4.1 MB
    float* cand_enc = (float*)ws;                 ws += (size_t)BATCH * NCAND * 300 * 4;
    float* user_rep = (float*)ws;                 ws += (size_t)BATCH * 300 * 4;
    ushort* his_qkvT  = (ushort*)ws;              ws += (size_t)NHIS * NQKV * KP * 2;
    ushort* his_wpT   = (ushort*)ws;              ws += (size_t)NHIS * NWP  * KP * 2;
    ushort* cand_qkvT = (ushort*)ws;              ws += (size_t)NCAND * NQKV * KP * 2;
    ushort* cand_wpT  = (ushort*)ws;              ws += (size_t)NCAND * NWP  * KP * 2;
    ushort* usr_qkvT  = (ushort*)ws;              ws += (size_t)NQKV * KP * 2;
    ushort* usr_wpT   = (ushort*)ws;              ws += (size_t)NWP  * KP * 2;

    size_t used = (size_t)(ws - (char*)d_ws);
    size_t avail = (ws_size > used) ? (ws_size - used) : 0;
    size_t qk_pp  = (size_t)3840 * NQK * 2;
    size_t vt_pp  = (size_t)BATCH * 15 * 640 * 2;
    size_t ctx_pp = (size_t)BATCH * 32 * CTS * 2;
    size_t per_p  = qk_pp + vt_pp + ctx_pp;
    int CP = (int)(avail / per_p);
    if (CP > 50) CP = 50;
    if (CP < 3) CP = 3;

    ushort* qk_ws  = (ushort*)ws;
    ushort* vt_ws  = qk_ws + (size_t)CP * 3840 * NQK;
    ushort* ctx_ws = vt_ws + (size_t)CP * BATCH * 15 * 640;

    ushort* qk_u  = qk_ws;                                // [6400][600]
    ushort* vt_u  = qk_u + (size_t)6400 * NQK;            // [128][15][20][64]
    ushort* ctx_u = vt_u + (size_t)BATCH * 15 * 20 * 64;  // [128][64][320]

    auto blocks = [](size_t total) { return (int)((total + 255) / 256); };

    hipMemsetAsync(news_enc_bf, 0, (size_t)BATCH * NHIS * KP * 2, stream);  // zero col pads
    prep_emb<<<blocks((size_t)VOCAB * (KP / 8)), 256, 0, stream>>>(emb, emb_bf);
    prep_qkv<<<blocks((size_t)NHIS  * NQKV * KP), 256, 0, stream>>>(his_Wq,  his_Wk,  his_Wv,  his_qkvT,  NHIS);
    prep_qkv<<<blocks((size_t)NCAND * NQKV * KP), 256, 0, stream>>>(cand_Wq, cand_Wk, cand_Wv, cand_qkvT, NCAND);
    prep_qkv<<<blocks((size_t)1     * NQKV * KP), 256, 0, stream>>>(usr_Wq,  usr_Wk,  usr_Wv,  usr_qkvT,  1);
    prep_wp <<<blocks((size_t)NHIS  * NWP  * KP), 256, 0, stream>>>(his_Wp,  his_wpT,  NHIS);
    prep_wp <<<blocks((size_t)NCAND * NWP  * KP), 256, 0, stream>>>(cand_Wp, cand_wpT, NCAND);
    prep_wp <<<blocks((size_t)1     * NWP  * KP), 256, 0, stream>>>(usr_Wp,  usr_wpT,  1);

    for (int p0 = 0; p0 < NHIS; p0 += CP) {
        int cp = (NHIS - p0 < CP) ? (NHIS - p0) : CP;
        int npmt = cp * 30;
        int S = ((npmt + 7) / 8) * 8;
        qkv_gemm<30, true><<<8 * S, 256, 0, stream>>>(emb_bf, news_input, his_qkvT, qk_ws, vt_ws, p0, NHIS, S, npmt);
        attn_ctx<<<cp * BATCH, 256, 0, stream>>>(qk_ws, vt_ws, ctx_ws, 0);
        pool_gemm<true><<<cp * 32, 256, 0, stream>>>(ctx_ws, his_wpT, his_bp, his_qv, nullptr, news_enc_bf, p0, NHIS);
    }
    {
        int npmt = NCAND * 30;
        int S = ((npmt + 7) / 8) * 8;
        qkv_gemm<30, true><<<8 * S, 256, 0, stream>>>(emb_bf, candidates, cand_qkvT, qk_ws, vt_ws, 0, NCAND, S, npmt);
        attn_ctx<<<NCAND * BATCH, 256, 0, stream>>>(qk_ws, vt_ws, ctx_ws, 0);
        pool_gemm<false><<<NCAND * 32, 256, 0, stream>>>(ctx_ws, cand_wpT, cand_bp, cand_qv, cand_enc, nullptr, 0, NCAND);
    }

    // user encoder
    hipMemsetAsync(vt_u, 0, (size_t)BATCH * 15 * 20 * 64 * 2, stream);
    {
        int npmt = 50;
        int S = 56;
        qkv_gemm<50, false><<<8 * S, 256, 0, stream>>>(news_enc_bf, nullptr, usr_qkvT, qk_u, vt_u, 0, 1, S, npmt);
    }
    attn50<<<BATCH, 512, 0, stream>>>(qk_u, vt_u, ctx_u);
    pool50<<<64, 256, 0, stream>>>(ctx_u, usr_wpT, usr_bp, usr_qv, user_rep);

    score_kernel<<<BATCH, 320, 0, stream>>>(user_rep, cand_enc, out);
}